// Round 1
// baseline (525.560 us; speedup 1.0000x reference)
//
#include <hip/hip_runtime.h>

static inline int ceil_div(int a, int b) { return (a + b - 1) / b; }

// ---------------- CSR build ----------------

__global__ void k_zero_int(int* __restrict__ p, int n) {
  int i = blockIdx.x * blockDim.x + threadIdx.x;
  if (i < n) p[i] = 0;
}

__global__ void k_count(const int* __restrict__ dst, int* __restrict__ cnt, int e) {
  int i = blockIdx.x * blockDim.x + threadIdx.x;
  if (i < e) atomicAdd(&cnt[dst[i]], 1);
}

__global__ void k_inv(const int* __restrict__ cnt, float* __restrict__ inv, int n) {
  int i = blockIdx.x * blockDim.x + threadIdx.x;
  if (i < n) inv[i] = 1.0f / (float)(cnt[i] > 1 ? cnt[i] : 1);
}

// single-block exclusive scan of cnt[0..n) -> row_ptr, cursor; row_ptr[n]=total
__global__ __launch_bounds__(1024) void k_scan(const int* __restrict__ cnt,
                                               int* __restrict__ row_ptr,
                                               int* __restrict__ cursor, int n) {
  __shared__ int s[1024];
  __shared__ int s_carry;
  const int tid = threadIdx.x;
  if (tid == 0) s_carry = 0;
  __syncthreads();
  const int VPT = 8;
  const int CHUNK = 1024 * VPT;
  for (int base = 0; base < n; base += CHUNK) {
    int vals[VPT];
    int sum = 0;
    int i0 = base + tid * VPT;
#pragma unroll
    for (int j = 0; j < VPT; ++j) {
      int i = i0 + j;
      int v = (i < n) ? cnt[i] : 0;
      vals[j] = sum;  // exclusive prefix within thread
      sum += v;
    }
    s[tid] = sum;
    __syncthreads();
    for (int off = 1; off < 1024; off <<= 1) {
      int t = (tid >= off) ? s[tid - off] : 0;
      __syncthreads();
      s[tid] += t;
      __syncthreads();
    }
    int thread_excl = s_carry + s[tid] - sum;
#pragma unroll
    for (int j = 0; j < VPT; ++j) {
      int i = i0 + j;
      if (i < n) {
        int e = thread_excl + vals[j];
        row_ptr[i] = e;
        cursor[i] = e;
      }
    }
    __syncthreads();
    if (tid == 1023) s_carry += s[1023];
    __syncthreads();
  }
  if (tid == 0) row_ptr[n] = s_carry;
}

__global__ void k_build_csr(const int* __restrict__ src, const int* __restrict__ dst,
                            int* __restrict__ cursor, int* __restrict__ csr_src, int e) {
  int i = blockIdx.x * blockDim.x + threadIdx.x;
  if (i < e) {
    int pos = atomicAdd(&cursor[dst[i]], 1);
    csr_src[pos] = src[i];
  }
}

// ---------------- dense per-row GEMV (FIN=128 fixed) ----------------
// out[g][:] = (ADD_AGG ? agg[g][:] + bias : 0) + hin[g][:] @ W ; optional ReLU
template <int FOUT, bool ADD_AGG, bool RELU>
__global__ __launch_bounds__(256) void k_gemv(const float* __restrict__ hin,
                                              const float* __restrict__ W,
                                              const float* __restrict__ bias,
                                              const float* __restrict__ agg,
                                              float* __restrict__ out, int n) {
  constexpr int CG = FOUT / 4;   // float4 column chunks
  constexpr int TR = 256 / CG;   // row-thread groups
  constexpr int RPT = 4;         // rows per thread
  constexpr int ROWS = TR * RPT; // rows per block
  constexpr int LDS_STRIDE = 132; // pad: banks differ by 4 per row -> <=2-way conflict
  __shared__ float s_rows[ROWS * LDS_STRIDE];

  const int tid = threadIdx.x;
  const int row0 = blockIdx.x * ROWS;

  // cooperative float4 load of ROWS x 128 input rows into LDS
  for (int i = tid; i < ROWS * 32; i += 256) {
    int r = i >> 5, c = i & 31;
    int g = row0 + r;
    float4 v = make_float4(0.f, 0.f, 0.f, 0.f);
    if (g < n) v = *(const float4*)(hin + (size_t)g * 128 + c * 4);
    *(float4*)(&s_rows[r * LDS_STRIDE + c * 4]) = v;
  }
  __syncthreads();

  const int tcol = tid % CG;
  const int trow = tid / CG;

  float4 acc[RPT];
#pragma unroll
  for (int r = 0; r < RPT; ++r) {
    if (ADD_AGG) {
      int g = row0 + trow * RPT + r;
      acc[r] = (g < n) ? *(const float4*)(agg + (size_t)g * FOUT + tcol * 4)
                       : make_float4(0.f, 0.f, 0.f, 0.f);
    } else {
      acc[r] = make_float4(0.f, 0.f, 0.f, 0.f);
    }
  }

  const float4* W4 = (const float4*)W;  // W is [128][FOUT] row-major
#pragma unroll 4
  for (int k = 0; k < 128; ++k) {
    float4 w = W4[k * CG + tcol];
#pragma unroll
    for (int r = 0; r < RPT; ++r) {
      float a = s_rows[(trow * RPT + r) * LDS_STRIDE + k];
      acc[r].x = fmaf(a, w.x, acc[r].x);
      acc[r].y = fmaf(a, w.y, acc[r].y);
      acc[r].z = fmaf(a, w.z, acc[r].z);
      acc[r].w = fmaf(a, w.w, acc[r].w);
    }
  }

  float4 bv = make_float4(0.f, 0.f, 0.f, 0.f);
  if (ADD_AGG) bv = ((const float4*)bias)[tcol];

#pragma unroll
  for (int r = 0; r < RPT; ++r) {
    int g = row0 + trow * RPT + r;
    if (g < n) {
      float4 v = acc[r];
      if (ADD_AGG) { v.x += bv.x; v.y += bv.y; v.z += bv.z; v.w += bv.w; }
      if (RELU) {
        v.x = fmaxf(v.x, 0.f); v.y = fmaxf(v.y, 0.f);
        v.z = fmaxf(v.z, 0.f); v.w = fmaxf(v.w, 0.f);
      }
      *(float4*)(out + (size_t)g * FOUT + tcol * 4) = v;
    }
  }
}

// ---------------- CSR mean-aggregation of Z ----------------
template <int FOUT>
__global__ __launch_bounds__(256) void k_aggregate(const float* __restrict__ Z,
                                                   const int* __restrict__ row_ptr,
                                                   const int* __restrict__ csr_src,
                                                   const float* __restrict__ inv,
                                                   float* __restrict__ agg, int n) {
  constexpr int CG = FOUT / 4;
  constexpr int NPB = 256 / CG;
  int node = blockIdx.x * NPB + threadIdx.x / CG;
  int c = threadIdx.x % CG;
  if (node >= n) return;
  int e0 = row_ptr[node], e1 = row_ptr[node + 1];
  float4 acc = make_float4(0.f, 0.f, 0.f, 0.f);
  for (int e = e0; e < e1; ++e) {
    int s = csr_src[e];
    float4 z = *(const float4*)(Z + (size_t)s * FOUT + c * 4);
    acc.x += z.x; acc.y += z.y; acc.z += z.z; acc.w += z.w;
  }
  float iv = inv[node];
  *(float4*)(agg + (size_t)node * FOUT + c * 4) =
      make_float4(acc.x * iv, acc.y * iv, acc.z * iv, acc.w * iv);
}

// ---------------- launch ----------------

extern "C" void kernel_launch(void* const* d_in, const int* in_sizes, int n_in,
                              void* d_out, int out_size, void* d_ws, size_t ws_size,
                              hipStream_t stream) {
  const float* x   = (const float*)d_in[0];
  const int*   ei  = (const int*)d_in[1];
  const float* Wl0 = (const float*)d_in[2];
  const float* bl0 = (const float*)d_in[3];
  const float* Wr0 = (const float*)d_in[4];
  const float* Wl1 = (const float*)d_in[5];
  const float* bl1 = (const float*)d_in[6];
  const float* Wr1 = (const float*)d_in[7];
  const float* Wl2 = (const float*)d_in[8];
  const float* bl2 = (const float*)d_in[9];
  const float* Wr2 = (const float*)d_in[10];
  float* out = (float*)d_out;

  const int N = in_sizes[0] / 128;
  const int E = in_sizes[1] / 2;
  const int* src = ei;
  const int* dst = ei + E;

  char* w = (char*)d_ws;
  auto alloc = [&](size_t bytes) {
    char* p = w;
    w += (bytes + 255) & ~(size_t)255;
    return p;
  };
  int*   cnt     = (int*)alloc((size_t)N * 4);
  int*   row_ptr = (int*)alloc((size_t)(N + 1) * 4);
  int*   cursor  = (int*)alloc((size_t)N * 4);
  int*   csr_src = (int*)alloc((size_t)E * 4);
  float* inv     = (float*)alloc((size_t)N * 4);
  float* B0      = (float*)alloc((size_t)N * 128 * 4);
  float* B1      = (float*)alloc((size_t)N * 128 * 4);
  float* B2      = (float*)alloc((size_t)N * 128 * 4);
  (void)ws_size; (void)n_in; (void)out_size;

  // ---- CSR build (per call; deterministic work) ----
  k_zero_int<<<ceil_div(N, 256), 256, 0, stream>>>(cnt, N);
  k_count<<<ceil_div(E, 256), 256, 0, stream>>>(dst, cnt, E);
  k_inv<<<ceil_div(N, 256), 256, 0, stream>>>(cnt, inv, N);
  k_scan<<<1, 1024, 0, stream>>>(cnt, row_ptr, cursor, N);
  k_build_csr<<<ceil_div(E, 256), 256, 0, stream>>>(src, dst, cursor, csr_src, E);

  // ---- layer 0: in=x, Z=B0, agg=B1, h1=B0 ----
  k_gemv<128, false, false><<<ceil_div(N, 32), 256, 0, stream>>>(x, Wl0, nullptr, nullptr, B0, N);
  k_aggregate<128><<<ceil_div(N, 8), 256, 0, stream>>>(B0, row_ptr, csr_src, inv, B1, N);
  k_gemv<128, true, true><<<ceil_div(N, 32), 256, 0, stream>>>(x, Wr0, bl0, B1, B0, N);

  // ---- layer 1: in=B0, Z=B1, agg=B2, h2=B1 ----
  k_gemv<128, false, false><<<ceil_div(N, 32), 256, 0, stream>>>(B0, Wl1, nullptr, nullptr, B1, N);
  k_aggregate<128><<<ceil_div(N, 8), 256, 0, stream>>>(B1, row_ptr, csr_src, inv, B2, N);
  k_gemv<128, true, true><<<ceil_div(N, 32), 256, 0, stream>>>(B0, Wr1, bl1, B2, B1, N);

  // ---- layer 2: in=B1, Z=B2 (N x 64), agg=B0, out=d_out ----
  k_gemv<64, false, false><<<ceil_div(N, 64), 256, 0, stream>>>(B1, Wl2, nullptr, nullptr, B2, N);
  k_aggregate<64><<<ceil_div(N, 16), 256, 0, stream>>>(B2, row_ptr, csr_src, inv, B0, N);
  k_gemv<64, true, false><<<ceil_div(N, 64), 256, 0, stream>>>(B1, Wr2, bl2, B0, out, N);
}

// Round 2
// 453.197 us; speedup vs baseline: 1.1597x; 1.1597x over previous
//
#include <hip/hip_runtime.h>

static inline int ceil_div(int a, int b) { return (a + b - 1) / b; }

// ---------------- CSR build ----------------

__global__ void k_zero_int(int* __restrict__ p, int n) {
  int i = blockIdx.x * blockDim.x + threadIdx.x;
  if (i < n) p[i] = 0;
}

__global__ void k_count(const int* __restrict__ dst, int* __restrict__ cnt, int e) {
  int i = blockIdx.x * blockDim.x + threadIdx.x;
  if (i < e) atomicAdd(&cnt[dst[i]], 1);
}

// ---- hierarchical scan: blocksum -> scan_partials -> scatter(+inv) ----
#define SCAN_BS 256
#define SCAN_VPT 4
#define SCAN_CHUNK (SCAN_BS * SCAN_VPT)

__global__ __launch_bounds__(SCAN_BS) void k_blocksum(const int* __restrict__ cnt,
                                                      int* __restrict__ partial, int n) {
  __shared__ int s[SCAN_BS / 64];
  const int tid = threadIdx.x;
  const int base = blockIdx.x * SCAN_CHUNK;
  int sum = 0;
#pragma unroll
  for (int j = 0; j < SCAN_VPT; ++j) {
    int i = base + tid + j * SCAN_BS;
    if (i < n) sum += cnt[i];
  }
  // wave reduce (64 lanes)
#pragma unroll
  for (int off = 32; off > 0; off >>= 1) sum += __shfl_down(sum, off, 64);
  if ((tid & 63) == 0) s[tid >> 6] = sum;
  __syncthreads();
  if (tid == 0) {
    int t = 0;
#pragma unroll
    for (int w = 0; w < SCAN_BS / 64; ++w) t += s[w];
    partial[blockIdx.x] = t;
  }
}

// single small block: exclusive-scan partial[0..p) in place; row_ptr[n_nodes]=total
__global__ __launch_bounds__(256) void k_scan_partials(int* __restrict__ partial, int p,
                                                       int* __restrict__ row_ptr, int n_nodes) {
  __shared__ int s[256];
  const int tid = threadIdx.x;
  int carry = 0;
  for (int base = 0; base < p; base += 256) {
    int i = base + tid;
    int v = (i < p) ? partial[i] : 0;
    s[tid] = v;
    __syncthreads();
    for (int off = 1; off < 256; off <<= 1) {
      int t = (tid >= off) ? s[tid - off] : 0;
      __syncthreads();
      s[tid] += t;
      __syncthreads();
    }
    if (i < p) partial[i] = carry + s[tid] - v;  // exclusive
    int tot = s[255];
    __syncthreads();
    carry += tot;
  }
  if (tid == 0) row_ptr[n_nodes] = carry;
}

__global__ __launch_bounds__(SCAN_BS) void k_scatter(const int* __restrict__ cnt,
                                                     const int* __restrict__ partial,
                                                     int* __restrict__ row_ptr,
                                                     int* __restrict__ cursor,
                                                     float* __restrict__ inv, int n) {
  __shared__ int s[SCAN_BS];
  const int tid = threadIdx.x;
  const int base = blockIdx.x * SCAN_CHUNK;
  const int i0 = base + tid * SCAN_VPT;
  int v[SCAN_VPT];
  int cv[SCAN_VPT];
  int sum = 0;
#pragma unroll
  for (int j = 0; j < SCAN_VPT; ++j) {
    int i = i0 + j;
    int c = (i < n) ? cnt[i] : 0;
    cv[j] = c;
    v[j] = sum;  // thread-local exclusive prefix
    sum += c;
  }
  s[tid] = sum;
  __syncthreads();
  for (int off = 1; off < SCAN_BS; off <<= 1) {
    int t = (tid >= off) ? s[tid - off] : 0;
    __syncthreads();
    s[tid] += t;
    __syncthreads();
  }
  const int excl = partial[blockIdx.x] + s[tid] - sum;
#pragma unroll
  for (int j = 0; j < SCAN_VPT; ++j) {
    int i = i0 + j;
    if (i < n) {
      int e = excl + v[j];
      row_ptr[i] = e;
      cursor[i] = e;
      inv[i] = 1.0f / (float)(cv[j] > 1 ? cv[j] : 1);
    }
  }
}

__global__ void k_build_csr(const int* __restrict__ src, const int* __restrict__ dst,
                            int* __restrict__ cursor, int* __restrict__ csr_src, int e) {
  int i = blockIdx.x * blockDim.x + threadIdx.x;
  if (i < e) {
    int pos = atomicAdd(&cursor[dst[i]], 1);
    csr_src[pos] = src[i];
  }
}

// ---------------- dense per-row GEMV (FIN=128 fixed) ----------------
// out[g][:] = (ADD_AGG ? agg[g][:] + bias : 0) + hin[g][:] @ W ; optional ReLU
template <int FOUT, bool ADD_AGG, bool RELU>
__global__ __launch_bounds__(256) void k_gemv(const float* __restrict__ hin,
                                              const float* __restrict__ W,
                                              const float* __restrict__ bias,
                                              const float* __restrict__ agg,
                                              float* __restrict__ out, int n) {
  constexpr int CG = FOUT / 4;   // float4 column chunks
  constexpr int TR = 256 / CG;   // row-thread groups
  constexpr int RPT = 4;         // rows per thread
  constexpr int ROWS = TR * RPT; // rows per block
  constexpr int LDS_STRIDE = 132; // pad: banks differ by 4 per row -> <=2-way conflict
  __shared__ float s_rows[ROWS * LDS_STRIDE];

  const int tid = threadIdx.x;
  const int row0 = blockIdx.x * ROWS;

  // cooperative float4 load of ROWS x 128 input rows into LDS
  for (int i = tid; i < ROWS * 32; i += 256) {
    int r = i >> 5, c = i & 31;
    int g = row0 + r;
    float4 v = make_float4(0.f, 0.f, 0.f, 0.f);
    if (g < n) v = *(const float4*)(hin + (size_t)g * 128 + c * 4);
    *(float4*)(&s_rows[r * LDS_STRIDE + c * 4]) = v;
  }
  __syncthreads();

  const int tcol = tid % CG;
  const int trow = tid / CG;

  float4 acc[RPT];
#pragma unroll
  for (int r = 0; r < RPT; ++r) {
    if (ADD_AGG) {
      int g = row0 + trow * RPT + r;
      acc[r] = (g < n) ? *(const float4*)(agg + (size_t)g * FOUT + tcol * 4)
                       : make_float4(0.f, 0.f, 0.f, 0.f);
    } else {
      acc[r] = make_float4(0.f, 0.f, 0.f, 0.f);
    }
  }

  const float4* W4 = (const float4*)W;  // W is [128][FOUT] row-major
#pragma unroll 4
  for (int k = 0; k < 128; ++k) {
    float4 w = W4[k * CG + tcol];
#pragma unroll
    for (int r = 0; r < RPT; ++r) {
      float a = s_rows[(trow * RPT + r) * LDS_STRIDE + k];
      acc[r].x = fmaf(a, w.x, acc[r].x);
      acc[r].y = fmaf(a, w.y, acc[r].y);
      acc[r].z = fmaf(a, w.z, acc[r].z);
      acc[r].w = fmaf(a, w.w, acc[r].w);
    }
  }

  float4 bv = make_float4(0.f, 0.f, 0.f, 0.f);
  if (ADD_AGG) bv = ((const float4*)bias)[tcol];

#pragma unroll
  for (int r = 0; r < RPT; ++r) {
    int g = row0 + trow * RPT + r;
    if (g < n) {
      float4 v = acc[r];
      if (ADD_AGG) { v.x += bv.x; v.y += bv.y; v.z += bv.z; v.w += bv.w; }
      if (RELU) {
        v.x = fmaxf(v.x, 0.f); v.y = fmaxf(v.y, 0.f);
        v.z = fmaxf(v.z, 0.f); v.w = fmaxf(v.w, 0.f);
      }
      *(float4*)(out + (size_t)g * FOUT + tcol * 4) = v;
    }
  }
}

// ---------------- CSR mean-aggregation of Z ----------------
template <int FOUT>
__global__ __launch_bounds__(256) void k_aggregate(const float* __restrict__ Z,
                                                   const int* __restrict__ row_ptr,
                                                   const int* __restrict__ csr_src,
                                                   const float* __restrict__ inv,
                                                   float* __restrict__ agg, int n) {
  constexpr int CG = FOUT / 4;
  constexpr int NPB = 256 / CG;
  int node = blockIdx.x * NPB + threadIdx.x / CG;
  int c = threadIdx.x % CG;
  if (node >= n) return;
  int e0 = row_ptr[node], e1 = row_ptr[node + 1];
  float4 acc = make_float4(0.f, 0.f, 0.f, 0.f);
  for (int e = e0; e < e1; ++e) {
    int s = csr_src[e];
    float4 z = *(const float4*)(Z + (size_t)s * FOUT + c * 4);
    acc.x += z.x; acc.y += z.y; acc.z += z.z; acc.w += z.w;
  }
  float iv = inv[node];
  *(float4*)(agg + (size_t)node * FOUT + c * 4) =
      make_float4(acc.x * iv, acc.y * iv, acc.z * iv, acc.w * iv);
}

// ---------------- launch ----------------

extern "C" void kernel_launch(void* const* d_in, const int* in_sizes, int n_in,
                              void* d_out, int out_size, void* d_ws, size_t ws_size,
                              hipStream_t stream) {
  const float* x   = (const float*)d_in[0];
  const int*   ei  = (const int*)d_in[1];
  const float* Wl0 = (const float*)d_in[2];
  const float* bl0 = (const float*)d_in[3];
  const float* Wr0 = (const float*)d_in[4];
  const float* Wl1 = (const float*)d_in[5];
  const float* bl1 = (const float*)d_in[6];
  const float* Wr1 = (const float*)d_in[7];
  const float* Wl2 = (const float*)d_in[8];
  const float* bl2 = (const float*)d_in[9];
  const float* Wr2 = (const float*)d_in[10];
  float* out = (float*)d_out;

  const int N = in_sizes[0] / 128;
  const int E = in_sizes[1] / 2;
  const int* src = ei;
  const int* dst = ei + E;

  char* w = (char*)d_ws;
  auto alloc = [&](size_t bytes) {
    char* p = w;
    w += (bytes + 255) & ~(size_t)255;
    return p;
  };
  int*   cnt     = (int*)alloc((size_t)N * 4);
  int*   row_ptr = (int*)alloc((size_t)(N + 1) * 4);
  int*   cursor  = (int*)alloc((size_t)N * 4);
  int*   csr_src = (int*)alloc((size_t)E * 4);
  float* inv     = (float*)alloc((size_t)N * 4);
  int*   partial = (int*)alloc((size_t)ceil_div(N, SCAN_CHUNK) * 4 + 256);
  float* B0      = (float*)alloc((size_t)N * 128 * 4);
  float* B1      = (float*)alloc((size_t)N * 128 * 4);
  float* B2      = (float*)alloc((size_t)N * 128 * 4);
  (void)ws_size; (void)n_in; (void)out_size;

  const int P = ceil_div(N, SCAN_CHUNK);

  // ---- CSR build (per call; deterministic work) ----
  k_zero_int<<<ceil_div(N, 256), 256, 0, stream>>>(cnt, N);
  k_count<<<ceil_div(E, 256), 256, 0, stream>>>(dst, cnt, E);
  k_blocksum<<<P, SCAN_BS, 0, stream>>>(cnt, partial, N);
  k_scan_partials<<<1, 256, 0, stream>>>(partial, P, row_ptr, N);
  k_scatter<<<P, SCAN_BS, 0, stream>>>(cnt, partial, row_ptr, cursor, inv, N);
  k_build_csr<<<ceil_div(E, 256), 256, 0, stream>>>(src, dst, cursor, csr_src, E);

  // ---- layer 0: in=x, Z=B0, agg=B1, h1=B0 ----
  k_gemv<128, false, false><<<ceil_div(N, 32), 256, 0, stream>>>(x, Wl0, nullptr, nullptr, B0, N);
  k_aggregate<128><<<ceil_div(N, 8), 256, 0, stream>>>(B0, row_ptr, csr_src, inv, B1, N);
  k_gemv<128, true, true><<<ceil_div(N, 32), 256, 0, stream>>>(x, Wr0, bl0, B1, B0, N);

  // ---- layer 1: in=B0, Z=B1, agg=B2, h2=B1 ----
  k_gemv<128, false, false><<<ceil_div(N, 32), 256, 0, stream>>>(B0, Wl1, nullptr, nullptr, B1, N);
  k_aggregate<128><<<ceil_div(N, 8), 256, 0, stream>>>(B1, row_ptr, csr_src, inv, B2, N);
  k_gemv<128, true, true><<<ceil_div(N, 32), 256, 0, stream>>>(B0, Wr1, bl1, B2, B1, N);

  // ---- layer 2: in=B1, Z=B2 (N x 64), agg=B0, out=d_out ----
  k_gemv<64, false, false><<<ceil_div(N, 64), 256, 0, stream>>>(B1, Wl2, nullptr, nullptr, B2, N);
  k_aggregate<64><<<ceil_div(N, 16), 256, 0, stream>>>(B2, row_ptr, csr_src, inv, B0, N);
  k_gemv<64, true, false><<<ceil_div(N, 64), 256, 0, stream>>>(B1, Wr2, bl2, B0, out, N);
}

// Round 3
// 440.297 us; speedup vs baseline: 1.1937x; 1.0293x over previous
//
#include <hip/hip_runtime.h>

static inline int ceil_div(int a, int b) { return (a + b - 1) / b; }

// ---------------- CSR build ----------------

__global__ void k_zero_int(int* __restrict__ p, int n) {
  int i = blockIdx.x * blockDim.x + threadIdx.x;
  if (i < n) p[i] = 0;
}

__global__ void k_count(const int* __restrict__ dst, int* __restrict__ cnt, int e) {
  int i = blockIdx.x * blockDim.x + threadIdx.x;
  if (i < e) atomicAdd(&cnt[dst[i]], 1);
}

// ---- hierarchical scan: blocksum -> scan_partials -> scatter(+inv) ----
#define SCAN_BS 256
#define SCAN_VPT 4
#define SCAN_CHUNK (SCAN_BS * SCAN_VPT)

__global__ __launch_bounds__(SCAN_BS) void k_blocksum(const int* __restrict__ cnt,
                                                      int* __restrict__ partial, int n) {
  __shared__ int s[SCAN_BS / 64];
  const int tid = threadIdx.x;
  const int base = blockIdx.x * SCAN_CHUNK;
  int sum = 0;
#pragma unroll
  for (int j = 0; j < SCAN_VPT; ++j) {
    int i = base + tid + j * SCAN_BS;
    if (i < n) sum += cnt[i];
  }
#pragma unroll
  for (int off = 32; off > 0; off >>= 1) sum += __shfl_down(sum, off, 64);
  if ((tid & 63) == 0) s[tid >> 6] = sum;
  __syncthreads();
  if (tid == 0) {
    int t = 0;
#pragma unroll
    for (int w = 0; w < SCAN_BS / 64; ++w) t += s[w];
    partial[blockIdx.x] = t;
  }
}

__global__ __launch_bounds__(256) void k_scan_partials(int* __restrict__ partial, int p,
                                                       int* __restrict__ row_ptr, int n_nodes) {
  __shared__ int s[256];
  const int tid = threadIdx.x;
  int carry = 0;
  for (int base = 0; base < p; base += 256) {
    int i = base + tid;
    int v = (i < p) ? partial[i] : 0;
    s[tid] = v;
    __syncthreads();
    for (int off = 1; off < 256; off <<= 1) {
      int t = (tid >= off) ? s[tid - off] : 0;
      __syncthreads();
      s[tid] += t;
      __syncthreads();
    }
    if (i < p) partial[i] = carry + s[tid] - v;  // exclusive
    int tot = s[255];
    __syncthreads();
    carry += tot;
  }
  if (tid == 0) row_ptr[n_nodes] = carry;
}

__global__ __launch_bounds__(SCAN_BS) void k_scatter(const int* __restrict__ cnt,
                                                     const int* __restrict__ partial,
                                                     int* __restrict__ row_ptr,
                                                     int* __restrict__ cursor,
                                                     float* __restrict__ inv, int n) {
  __shared__ int s[SCAN_BS];
  const int tid = threadIdx.x;
  const int base = blockIdx.x * SCAN_CHUNK;
  const int i0 = base + tid * SCAN_VPT;
  int v[SCAN_VPT];
  int cv[SCAN_VPT];
  int sum = 0;
#pragma unroll
  for (int j = 0; j < SCAN_VPT; ++j) {
    int i = i0 + j;
    int c = (i < n) ? cnt[i] : 0;
    cv[j] = c;
    v[j] = sum;
    sum += c;
  }
  s[tid] = sum;
  __syncthreads();
  for (int off = 1; off < SCAN_BS; off <<= 1) {
    int t = (tid >= off) ? s[tid - off] : 0;
    __syncthreads();
    s[tid] += t;
    __syncthreads();
  }
  const int excl = partial[blockIdx.x] + s[tid] - sum;
#pragma unroll
  for (int j = 0; j < SCAN_VPT; ++j) {
    int i = i0 + j;
    if (i < n) {
      int e = excl + v[j];
      row_ptr[i] = e;
      cursor[i] = e;
      inv[i] = 1.0f / (float)(cv[j] > 1 ? cv[j] : 1);
    }
  }
}

__global__ void k_build_csr(const int* __restrict__ src, const int* __restrict__ dst,
                            int* __restrict__ cursor, int* __restrict__ csr_src, int e) {
  int i = blockIdx.x * blockDim.x + threadIdx.x;
  if (i < e) {
    int pos = atomicAdd(&cursor[dst[i]], 1);
    csr_src[pos] = src[i];
  }
}

// ---------------- fused dual GEMV: Z = hin@Wl ; R = hin@Wr + b (FIN=128) ----
template <int FOUT>
__global__ __launch_bounds__(256) void k_gemv2(const float* __restrict__ hin,
                                               const float* __restrict__ Wl,
                                               const float* __restrict__ Wr,
                                               const float* __restrict__ bias,
                                               float* __restrict__ Z,
                                               float* __restrict__ R, int n) {
  constexpr int CG = FOUT / 4;    // float4 column chunks (32 or 16)
  constexpr int TR = 256 / CG;    // row-thread groups
  constexpr int RPT = 4;
  constexpr int ROWS = TR * RPT;  // 32 or 64
  constexpr int LDS_STRIDE = 132; // 132*4B = 528B, 16B-aligned; wave's trow groups hit disjoint bank quads
  __shared__ float s_rows[ROWS * LDS_STRIDE];

  const int tid = threadIdx.x;
  const int row0 = blockIdx.x * ROWS;

  for (int i = tid; i < ROWS * 32; i += 256) {
    int r = i >> 5, c = i & 31;
    int g = row0 + r;
    float4 v = make_float4(0.f, 0.f, 0.f, 0.f);
    if (g < n) v = *(const float4*)(hin + (size_t)g * 128 + c * 4);
    *(float4*)(&s_rows[r * LDS_STRIDE + c * 4]) = v;
  }
  __syncthreads();

  const int tcol = tid % CG;
  const int trow = tid / CG;

  const float4 bv = ((const float4*)bias)[tcol];
  float4 accZ[RPT], accR[RPT];
#pragma unroll
  for (int r = 0; r < RPT; ++r) {
    accZ[r] = make_float4(0.f, 0.f, 0.f, 0.f);
    accR[r] = bv;
  }

  const float4* Wl4 = (const float4*)Wl;  // [128][FOUT] row-major
  const float4* Wr4 = (const float4*)Wr;

  for (int k4 = 0; k4 < 128; k4 += 4) {
    float4 a[RPT];
#pragma unroll
    for (int r = 0; r < RPT; ++r)
      a[r] = *(const float4*)(&s_rows[(trow * RPT + r) * LDS_STRIDE + k4]);
#pragma unroll
    for (int kk = 0; kk < 4; ++kk) {
      float4 wl = Wl4[(k4 + kk) * CG + tcol];
      float4 wr = Wr4[(k4 + kk) * CG + tcol];
#pragma unroll
      for (int r = 0; r < RPT; ++r) {
        float av = ((const float*)&a[r])[kk];
        accZ[r].x = fmaf(av, wl.x, accZ[r].x);
        accZ[r].y = fmaf(av, wl.y, accZ[r].y);
        accZ[r].z = fmaf(av, wl.z, accZ[r].z);
        accZ[r].w = fmaf(av, wl.w, accZ[r].w);
        accR[r].x = fmaf(av, wr.x, accR[r].x);
        accR[r].y = fmaf(av, wr.y, accR[r].y);
        accR[r].z = fmaf(av, wr.z, accR[r].z);
        accR[r].w = fmaf(av, wr.w, accR[r].w);
      }
    }
  }

#pragma unroll
  for (int r = 0; r < RPT; ++r) {
    int g = row0 + trow * RPT + r;
    if (g < n) {
      *(float4*)(Z + (size_t)g * FOUT + tcol * 4) = accZ[r];
      *(float4*)(R + (size_t)g * FOUT + tcol * 4) = accR[r];
    }
  }
}

// -------- CSR mean-aggregation + epilogue: out = act(mean(Z)*inv + R) --------
// One wave per node; lanes = EG edge-groups x FL feature lanes; edge loop
// unrolled x4 with clamped indices -> up to 8 gathers in flight per wave.
template <int FOUT, bool RELU>
__global__ __launch_bounds__(256) void k_agg2(const float* __restrict__ Z,
                                              const float* __restrict__ R,
                                              const int* __restrict__ row_ptr,
                                              const int* __restrict__ csr_src,
                                              const float* __restrict__ inv,
                                              float* __restrict__ outp, int n) {
  constexpr int FL = FOUT / 4;  // feature lanes (32 or 16)
  constexpr int EG = 64 / FL;   // edge groups per wave (2 or 4)
  const int lane = threadIdx.x & 63;
  const int node = blockIdx.x * 4 + (threadIdx.x >> 6);
  if (node >= n) return;
  const int c = lane % FL;
  const int eg = lane / FL;

  const int e0 = row_ptr[node];
  const int m = row_ptr[node + 1] - e0;  // wave-uniform
  const float4* Z4 = (const float4*)Z;

  float4 acc = make_float4(0.f, 0.f, 0.f, 0.f);
  int t = eg;
  while (t < m) {
    int ss[4];
#pragma unroll
    for (int j = 0; j < 4; ++j) {
      int tj = t + j * EG;
      int tc = (tj < m) ? tj : (m - 1);  // clamped: always valid
      ss[j] = csr_src[e0 + tc];
    }
    float4 z[4];
#pragma unroll
    for (int j = 0; j < 4; ++j) z[j] = Z4[(size_t)ss[j] * FL + c];
#pragma unroll
    for (int j = 0; j < 4; ++j) {
      if (t + j * EG < m) {
        acc.x += z[j].x; acc.y += z[j].y; acc.z += z[j].z; acc.w += z[j].w;
      }
    }
    t += 4 * EG;
  }

#pragma unroll
  for (int off = FL; off < 64; off <<= 1) {
    acc.x += __shfl_xor(acc.x, off, 64);
    acc.y += __shfl_xor(acc.y, off, 64);
    acc.z += __shfl_xor(acc.z, off, 64);
    acc.w += __shfl_xor(acc.w, off, 64);
  }

  if (eg == 0) {
    const float iv = inv[node];
    float4 r = ((const float4*)R)[(size_t)node * FL + c];
    float4 o;
    o.x = fmaf(acc.x, iv, r.x);
    o.y = fmaf(acc.y, iv, r.y);
    o.z = fmaf(acc.z, iv, r.z);
    o.w = fmaf(acc.w, iv, r.w);
    if (RELU) {
      o.x = fmaxf(o.x, 0.f); o.y = fmaxf(o.y, 0.f);
      o.z = fmaxf(o.z, 0.f); o.w = fmaxf(o.w, 0.f);
    }
    *(float4*)(outp + (size_t)node * FOUT + c * 4) = o;
  }
}

// ---------------- launch ----------------

extern "C" void kernel_launch(void* const* d_in, const int* in_sizes, int n_in,
                              void* d_out, int out_size, void* d_ws, size_t ws_size,
                              hipStream_t stream) {
  const float* x   = (const float*)d_in[0];
  const int*   ei  = (const int*)d_in[1];
  const float* Wl0 = (const float*)d_in[2];
  const float* bl0 = (const float*)d_in[3];
  const float* Wr0 = (const float*)d_in[4];
  const float* Wl1 = (const float*)d_in[5];
  const float* bl1 = (const float*)d_in[6];
  const float* Wr1 = (const float*)d_in[7];
  const float* Wl2 = (const float*)d_in[8];
  const float* bl2 = (const float*)d_in[9];
  const float* Wr2 = (const float*)d_in[10];
  float* out = (float*)d_out;

  const int N = in_sizes[0] / 128;
  const int E = in_sizes[1] / 2;
  const int* src = ei;
  const int* dst = ei + E;

  char* w = (char*)d_ws;
  auto alloc = [&](size_t bytes) {
    char* p = w;
    w += (bytes + 255) & ~(size_t)255;
    return p;
  };
  int*   cnt     = (int*)alloc((size_t)N * 4);
  int*   row_ptr = (int*)alloc((size_t)(N + 1) * 4);
  int*   cursor  = (int*)alloc((size_t)N * 4);
  int*   csr_src = (int*)alloc((size_t)E * 4 + 256);
  float* inv     = (float*)alloc((size_t)N * 4);
  int*   partial = (int*)alloc((size_t)ceil_div(N, SCAN_CHUNK) * 4 + 256);
  float* BZ      = (float*)alloc((size_t)N * 128 * 4);
  float* BR      = (float*)alloc((size_t)N * 128 * 4);
  float* B0      = (float*)alloc((size_t)N * 128 * 4);
  (void)ws_size; (void)n_in; (void)out_size;

  const int P = ceil_div(N, SCAN_CHUNK);

  // ---- CSR build ----
  k_zero_int<<<ceil_div(N, 256), 256, 0, stream>>>(cnt, N);
  k_count<<<ceil_div(E, 256), 256, 0, stream>>>(dst, cnt, E);
  k_blocksum<<<P, SCAN_BS, 0, stream>>>(cnt, partial, N);
  k_scan_partials<<<1, 256, 0, stream>>>(partial, P, row_ptr, N);
  k_scatter<<<P, SCAN_BS, 0, stream>>>(cnt, partial, row_ptr, cursor, inv, N);
  k_build_csr<<<ceil_div(E, 256), 256, 0, stream>>>(src, dst, cursor, csr_src, E);

  // ---- layer 0: x -> (Z,R) -> H1 (B0) ----
  k_gemv2<128><<<ceil_div(N, 32), 256, 0, stream>>>(x, Wl0, Wr0, bl0, BZ, BR, N);
  k_agg2<128, true><<<ceil_div(N, 4), 256, 0, stream>>>(BZ, BR, row_ptr, csr_src, inv, B0, N);

  // ---- layer 1: B0 -> (Z,R) -> H2 (B0) ----
  k_gemv2<128><<<ceil_div(N, 32), 256, 0, stream>>>(B0, Wl1, Wr1, bl1, BZ, BR, N);
  k_agg2<128, true><<<ceil_div(N, 4), 256, 0, stream>>>(BZ, BR, row_ptr, csr_src, inv, B0, N);

  // ---- layer 2: B0 -> (Z,R) 64-wide -> out ----
  k_gemv2<64><<<ceil_div(N, 64), 256, 0, stream>>>(B0, Wl2, Wr2, bl2, BZ, BR, N);
  k_agg2<64, false><<<ceil_div(N, 4), 256, 0, stream>>>(BZ, BR, row_ptr, csr_src, inv, out, N);
}

// Round 4
// 415.834 us; speedup vs baseline: 1.2639x; 1.0588x over previous
//
#include <hip/hip_runtime.h>

static inline int ceil_div(int a, int b) { return (a + b - 1) / b; }

// ---------------- CSR build ----------------

__global__ void k_zero_int(int* __restrict__ p, int n) {
  int i = blockIdx.x * blockDim.x + threadIdx.x;
  if (i < n) p[i] = 0;
}

__global__ void k_count(const int* __restrict__ dst, int* __restrict__ cnt, int e) {
  int i = blockIdx.x * blockDim.x + threadIdx.x;
  if (i < e) atomicAdd(&cnt[dst[i]], 1);
}

// ---- hierarchical scan: blocksum -> scan_partials -> scatter(+inv) ----
#define SCAN_BS 256
#define SCAN_VPT 4
#define SCAN_CHUNK (SCAN_BS * SCAN_VPT)

__global__ __launch_bounds__(SCAN_BS) void k_blocksum(const int* __restrict__ cnt,
                                                      int* __restrict__ partial, int n) {
  __shared__ int s[SCAN_BS / 64];
  const int tid = threadIdx.x;
  const int base = blockIdx.x * SCAN_CHUNK;
  int sum = 0;
#pragma unroll
  for (int j = 0; j < SCAN_VPT; ++j) {
    int i = base + tid + j * SCAN_BS;
    if (i < n) sum += cnt[i];
  }
#pragma unroll
  for (int off = 32; off > 0; off >>= 1) sum += __shfl_down(sum, off, 64);
  if ((tid & 63) == 0) s[tid >> 6] = sum;
  __syncthreads();
  if (tid == 0) {
    int t = 0;
#pragma unroll
    for (int w = 0; w < SCAN_BS / 64; ++w) t += s[w];
    partial[blockIdx.x] = t;
  }
}

__global__ __launch_bounds__(256) void k_scan_partials(int* __restrict__ partial, int p,
                                                       int* __restrict__ row_ptr, int n_nodes) {
  __shared__ int s[256];
  const int tid = threadIdx.x;
  int carry = 0;
  for (int base = 0; base < p; base += 256) {
    int i = base + tid;
    int v = (i < p) ? partial[i] : 0;
    s[tid] = v;
    __syncthreads();
    for (int off = 1; off < 256; off <<= 1) {
      int t = (tid >= off) ? s[tid - off] : 0;
      __syncthreads();
      s[tid] += t;
      __syncthreads();
    }
    if (i < p) partial[i] = carry + s[tid] - v;  // exclusive
    int tot = s[255];
    __syncthreads();
    carry += tot;
  }
  if (tid == 0) row_ptr[n_nodes] = carry;
}

__global__ __launch_bounds__(SCAN_BS) void k_scatter(const int* __restrict__ cnt,
                                                     const int* __restrict__ partial,
                                                     int* __restrict__ row_ptr,
                                                     int* __restrict__ cursor,
                                                     float* __restrict__ inv, int n) {
  __shared__ int s[SCAN_BS];
  const int tid = threadIdx.x;
  const int base = blockIdx.x * SCAN_CHUNK;
  const int i0 = base + tid * SCAN_VPT;
  int v[SCAN_VPT];
  int cv[SCAN_VPT];
  int sum = 0;
#pragma unroll
  for (int j = 0; j < SCAN_VPT; ++j) {
    int i = i0 + j;
    int c = (i < n) ? cnt[i] : 0;
    cv[j] = c;
    v[j] = sum;
    sum += c;
  }
  s[tid] = sum;
  __syncthreads();
  for (int off = 1; off < SCAN_BS; off <<= 1) {
    int t = (tid >= off) ? s[tid - off] : 0;
    __syncthreads();
    s[tid] += t;
    __syncthreads();
  }
  const int excl = partial[blockIdx.x] + s[tid] - sum;
#pragma unroll
  for (int j = 0; j < SCAN_VPT; ++j) {
    int i = i0 + j;
    if (i < n) {
      int e = excl + v[j];
      row_ptr[i] = e;
      cursor[i] = e;
      inv[i] = 1.0f / (float)(cv[j] > 1 ? cv[j] : 1);
    }
  }
}

__global__ void k_build_csr(const int* __restrict__ src, const int* __restrict__ dst,
                            int* __restrict__ cursor, int* __restrict__ csr_src, int e) {
  int i = blockIdx.x * blockDim.x + threadIdx.x;
  if (i < e) {
    int pos = atomicAdd(&cursor[dst[i]], 1);
    csr_src[pos] = src[i];
  }
}

// ---------------- fused dual GEMV: Z = hin@Wl ; R = hin@Wr + b (FIN=128) ----
// Register double-buffered weight prefetch: next k4-group's 8 float4 weight
// loads are issued BEFORE the current group's FMAs, so the L2 round-trip
// hides under ~256 cycles of VALU work (issue-early / consume-late).
template <int FOUT, int RPT>
__global__ __launch_bounds__(256) void k_gemv2(const float* __restrict__ hin,
                                               const float* __restrict__ Wl,
                                               const float* __restrict__ Wr,
                                               const float* __restrict__ bias,
                                               float* __restrict__ Z,
                                               float* __restrict__ R, int n) {
  constexpr int CG = FOUT / 4;    // float4 column chunks (32 or 16)
  constexpr int TR = 256 / CG;    // row-thread groups
  constexpr int ROWS = TR * RPT;
  constexpr int LDS_STRIDE = 132;
  __shared__ float s_rows[ROWS * LDS_STRIDE];

  const int tid = threadIdx.x;
  const int row0 = blockIdx.x * ROWS;

  for (int i = tid; i < ROWS * 32; i += 256) {
    int r = i >> 5, c = i & 31;
    int g = row0 + r;
    float4 v = make_float4(0.f, 0.f, 0.f, 0.f);
    if (g < n) v = *(const float4*)(hin + (size_t)g * 128 + c * 4);
    *(float4*)(&s_rows[r * LDS_STRIDE + c * 4]) = v;
  }
  __syncthreads();

  const int tcol = tid % CG;
  const int trow = tid / CG;
  const float* arow = &s_rows[trow * RPT * LDS_STRIDE];

  const float4 bv = ((const float4*)bias)[tcol];
  float4 accZ[RPT], accR[RPT];
#pragma unroll
  for (int r = 0; r < RPT; ++r) {
    accZ[r] = make_float4(0.f, 0.f, 0.f, 0.f);
    accR[r] = bv;
  }

  const float4* Wl4 = (const float4*)Wl;  // [128][FOUT] row-major
  const float4* Wr4 = (const float4*)Wr;

  float4 wlA[4], wrA[4], wlB[4], wrB[4];

#define LOADW(WLBUF, WRBUF, K4)                          \
  {                                                      \
    _Pragma("unroll") for (int kk = 0; kk < 4; ++kk) {   \
      (WLBUF)[kk] = Wl4[((K4) + kk) * CG + tcol];        \
      (WRBUF)[kk] = Wr4[((K4) + kk) * CG + tcol];        \
    }                                                    \
  }

#define COMP(WLBUF, WRBUF, K4)                                        \
  {                                                                   \
    float4 a[RPT];                                                    \
    _Pragma("unroll") for (int r = 0; r < RPT; ++r)                   \
        a[r] = *(const float4*)(&arow[r * LDS_STRIDE + (K4)]);        \
    _Pragma("unroll") for (int kk = 0; kk < 4; ++kk) {                \
      _Pragma("unroll") for (int r = 0; r < RPT; ++r) {               \
        float av = ((const float*)&a[r])[kk];                         \
        accZ[r].x = fmaf(av, (WLBUF)[kk].x, accZ[r].x);               \
        accZ[r].y = fmaf(av, (WLBUF)[kk].y, accZ[r].y);               \
        accZ[r].z = fmaf(av, (WLBUF)[kk].z, accZ[r].z);               \
        accZ[r].w = fmaf(av, (WLBUF)[kk].w, accZ[r].w);               \
        accR[r].x = fmaf(av, (WRBUF)[kk].x, accR[r].x);               \
        accR[r].y = fmaf(av, (WRBUF)[kk].y, accR[r].y);               \
        accR[r].z = fmaf(av, (WRBUF)[kk].z, accR[r].z);               \
        accR[r].w = fmaf(av, (WRBUF)[kk].w, accR[r].w);               \
      }                                                               \
    }                                                                 \
  }

  LOADW(wlA, wrA, 0);
  for (int k8 = 0; k8 < 128; k8 += 8) {
    LOADW(wlB, wrB, k8 + 4);
    COMP(wlA, wrA, k8);
    if (k8 + 8 < 128) LOADW(wlA, wrA, k8 + 8);
    COMP(wlB, wrB, k8 + 4);
  }
#undef LOADW
#undef COMP

#pragma unroll
  for (int r = 0; r < RPT; ++r) {
    int g = row0 + trow * RPT + r;
    if (g < n) {
      *(float4*)(Z + (size_t)g * FOUT + tcol * 4) = accZ[r];
      *(float4*)(R + (size_t)g * FOUT + tcol * 4) = accR[r];
    }
  }
}

// -------- CSR mean-aggregation + epilogue: out = act(mean(Z)*inv + R) --------
template <int FOUT, bool RELU>
__global__ __launch_bounds__(256) void k_agg2(const float* __restrict__ Z,
                                              const float* __restrict__ R,
                                              const int* __restrict__ row_ptr,
                                              const int* __restrict__ csr_src,
                                              const float* __restrict__ inv,
                                              float* __restrict__ outp, int n) {
  constexpr int FL = FOUT / 4;  // feature lanes (32 or 16)
  constexpr int EG = 64 / FL;   // edge groups per wave (2 or 4)
  const int lane = threadIdx.x & 63;
  const int node = blockIdx.x * 4 + (threadIdx.x >> 6);
  if (node >= n) return;
  const int c = lane % FL;
  const int eg = lane / FL;

  const int e0 = row_ptr[node];
  const int m = row_ptr[node + 1] - e0;  // wave-uniform
  const float4* Z4 = (const float4*)Z;

  float4 acc = make_float4(0.f, 0.f, 0.f, 0.f);
  int t = eg;
  while (t < m) {
    int ss[4];
#pragma unroll
    for (int j = 0; j < 4; ++j) {
      int tj = t + j * EG;
      int tc = (tj < m) ? tj : (m - 1);  // clamped: always valid
      ss[j] = csr_src[e0 + tc];
    }
    float4 z[4];
#pragma unroll
    for (int j = 0; j < 4; ++j) z[j] = Z4[(size_t)ss[j] * FL + c];
#pragma unroll
    for (int j = 0; j < 4; ++j) {
      if (t + j * EG < m) {
        acc.x += z[j].x; acc.y += z[j].y; acc.z += z[j].z; acc.w += z[j].w;
      }
    }
    t += 4 * EG;
  }

#pragma unroll
  for (int off = FL; off < 64; off <<= 1) {
    acc.x += __shfl_xor(acc.x, off, 64);
    acc.y += __shfl_xor(acc.y, off, 64);
    acc.z += __shfl_xor(acc.z, off, 64);
    acc.w += __shfl_xor(acc.w, off, 64);
  }

  if (eg == 0) {
    const float iv = inv[node];
    float4 r = ((const float4*)R)[(size_t)node * FL + c];
    float4 o;
    o.x = fmaf(acc.x, iv, r.x);
    o.y = fmaf(acc.y, iv, r.y);
    o.z = fmaf(acc.z, iv, r.z);
    o.w = fmaf(acc.w, iv, r.w);
    if (RELU) {
      o.x = fmaxf(o.x, 0.f); o.y = fmaxf(o.y, 0.f);
      o.z = fmaxf(o.z, 0.f); o.w = fmaxf(o.w, 0.f);
    }
    *(float4*)(outp + (size_t)node * FOUT + c * 4) = o;
  }
}

// ---------------- launch ----------------

extern "C" void kernel_launch(void* const* d_in, const int* in_sizes, int n_in,
                              void* d_out, int out_size, void* d_ws, size_t ws_size,
                              hipStream_t stream) {
  const float* x   = (const float*)d_in[0];
  const int*   ei  = (const int*)d_in[1];
  const float* Wl0 = (const float*)d_in[2];
  const float* bl0 = (const float*)d_in[3];
  const float* Wr0 = (const float*)d_in[4];
  const float* Wl1 = (const float*)d_in[5];
  const float* bl1 = (const float*)d_in[6];
  const float* Wr1 = (const float*)d_in[7];
  const float* Wl2 = (const float*)d_in[8];
  const float* bl2 = (const float*)d_in[9];
  const float* Wr2 = (const float*)d_in[10];
  float* out = (float*)d_out;

  const int N = in_sizes[0] / 128;
  const int E = in_sizes[1] / 2;
  const int* src = ei;
  const int* dst = ei + E;

  char* w = (char*)d_ws;
  auto alloc = [&](size_t bytes) {
    char* p = w;
    w += (bytes + 255) & ~(size_t)255;
    return p;
  };
  int*   cnt     = (int*)alloc((size_t)N * 4);
  int*   row_ptr = (int*)alloc((size_t)(N + 1) * 4);
  int*   cursor  = (int*)alloc((size_t)N * 4);
  int*   csr_src = (int*)alloc((size_t)E * 4 + 256);
  float* inv     = (float*)alloc((size_t)N * 4);
  int*   partial = (int*)alloc((size_t)ceil_div(N, SCAN_CHUNK) * 4 + 256);
  float* BZ      = (float*)alloc((size_t)N * 128 * 4);
  float* BR      = (float*)alloc((size_t)N * 128 * 4);
  float* B0      = (float*)alloc((size_t)N * 128 * 4);
  (void)ws_size; (void)n_in; (void)out_size;

  const int P = ceil_div(N, SCAN_CHUNK);

  // ---- CSR build ----
  k_zero_int<<<ceil_div(N, 256), 256, 0, stream>>>(cnt, N);
  k_count<<<ceil_div(E, 256), 256, 0, stream>>>(dst, cnt, E);
  k_blocksum<<<P, SCAN_BS, 0, stream>>>(cnt, partial, N);
  k_scan_partials<<<1, 256, 0, stream>>>(partial, P, row_ptr, N);
  k_scatter<<<P, SCAN_BS, 0, stream>>>(cnt, partial, row_ptr, cursor, inv, N);
  k_build_csr<<<ceil_div(E, 256), 256, 0, stream>>>(src, dst, cursor, csr_src, E);

  // ---- layer 0: x -> (Z,R) -> H1 (B0) ----
  k_gemv2<128, 4><<<ceil_div(N, 32), 256, 0, stream>>>(x, Wl0, Wr0, bl0, BZ, BR, N);
  k_agg2<128, true><<<ceil_div(N, 4), 256, 0, stream>>>(BZ, BR, row_ptr, csr_src, inv, B0, N);

  // ---- layer 1: B0 -> (Z,R) -> H2 (B0) ----
  k_gemv2<128, 4><<<ceil_div(N, 32), 256, 0, stream>>>(B0, Wl1, Wr1, bl1, BZ, BR, N);
  k_agg2<128, true><<<ceil_div(N, 4), 256, 0, stream>>>(BZ, BR, row_ptr, csr_src, inv, B0, N);

  // ---- layer 2: B0 -> (Z,R) 64-wide -> out ----
  k_gemv2<64, 4><<<ceil_div(N, 64), 256, 0, stream>>>(B0, Wl2, Wr2, bl2, BZ, BR, N);
  k_agg2<64, false><<<ceil_div(N, 4), 256, 0, stream>>>(BZ, BR, row_ptr, csr_src, inv, out, N);
}

// Round 5
// 336.800 us; speedup vs baseline: 1.5605x; 1.2347x over previous
//
#include <hip/hip_runtime.h>

static inline int ceil_div(int a, int b) { return (a + b - 1) / b; }

typedef __attribute__((ext_vector_type(8))) short short8;   // 8 bf16 = 4 VGPR
typedef __attribute__((ext_vector_type(4))) float f32x4;

// ---------------- CSR build ----------------

__global__ void k_zero_int(int* __restrict__ p, int n) {
  int i = blockIdx.x * blockDim.x + threadIdx.x;
  if (i < n) p[i] = 0;
}

__global__ void k_count(const int* __restrict__ dst, int* __restrict__ cnt, int e) {
  int i = blockIdx.x * blockDim.x + threadIdx.x;
  if (i < e) atomicAdd(&cnt[dst[i]], 1);
}

#define SCAN_BS 256
#define SCAN_VPT 4
#define SCAN_CHUNK (SCAN_BS * SCAN_VPT)

__global__ __launch_bounds__(SCAN_BS) void k_blocksum(const int* __restrict__ cnt,
                                                      int* __restrict__ partial, int n) {
  __shared__ int s[SCAN_BS / 64];
  const int tid = threadIdx.x;
  const int base = blockIdx.x * SCAN_CHUNK;
  int sum = 0;
#pragma unroll
  for (int j = 0; j < SCAN_VPT; ++j) {
    int i = base + tid + j * SCAN_BS;
    if (i < n) sum += cnt[i];
  }
#pragma unroll
  for (int off = 32; off > 0; off >>= 1) sum += __shfl_down(sum, off, 64);
  if ((tid & 63) == 0) s[tid >> 6] = sum;
  __syncthreads();
  if (tid == 0) {
    int t = 0;
#pragma unroll
    for (int w = 0; w < SCAN_BS / 64; ++w) t += s[w];
    partial[blockIdx.x] = t;
  }
}

__global__ __launch_bounds__(256) void k_scan_partials(int* __restrict__ partial, int p,
                                                       int* __restrict__ row_ptr, int n_nodes) {
  __shared__ int s[256];
  const int tid = threadIdx.x;
  int carry = 0;
  for (int base = 0; base < p; base += 256) {
    int i = base + tid;
    int v = (i < p) ? partial[i] : 0;
    s[tid] = v;
    __syncthreads();
    for (int off = 1; off < 256; off <<= 1) {
      int t = (tid >= off) ? s[tid - off] : 0;
      __syncthreads();
      s[tid] += t;
      __syncthreads();
    }
    if (i < p) partial[i] = carry + s[tid] - v;  // exclusive
    int tot = s[255];
    __syncthreads();
    carry += tot;
  }
  if (tid == 0) row_ptr[n_nodes] = carry;
}

__global__ __launch_bounds__(SCAN_BS) void k_scatter(const int* __restrict__ cnt,
                                                     const int* __restrict__ partial,
                                                     int* __restrict__ row_ptr,
                                                     int* __restrict__ cursor,
                                                     float* __restrict__ inv, int n) {
  __shared__ int s[SCAN_BS];
  const int tid = threadIdx.x;
  const int base = blockIdx.x * SCAN_CHUNK;
  const int i0 = base + tid * SCAN_VPT;
  int v[SCAN_VPT];
  int cv[SCAN_VPT];
  int sum = 0;
#pragma unroll
  for (int j = 0; j < SCAN_VPT; ++j) {
    int i = i0 + j;
    int c = (i < n) ? cnt[i] : 0;
    cv[j] = c;
    v[j] = sum;
    sum += c;
  }
  s[tid] = sum;
  __syncthreads();
  for (int off = 1; off < SCAN_BS; off <<= 1) {
    int t = (tid >= off) ? s[tid - off] : 0;
    __syncthreads();
    s[tid] += t;
    __syncthreads();
  }
  const int excl = partial[blockIdx.x] + s[tid] - sum;
#pragma unroll
  for (int j = 0; j < SCAN_VPT; ++j) {
    int i = i0 + j;
    if (i < n) {
      int e = excl + v[j];
      row_ptr[i] = e;
      cursor[i] = e;
      inv[i] = 1.0f / (float)(cv[j] > 1 ? cv[j] : 1);
    }
  }
}

__global__ void k_build_csr(const int* __restrict__ src, const int* __restrict__ dst,
                            int* __restrict__ cursor, int* __restrict__ csr_src, int e) {
  int i = blockIdx.x * blockDim.x + threadIdx.x;
  if (i < e) {
    int pos = atomicAdd(&cursor[dst[i]], 1);
    csr_src[pos] = src[i];
  }
}

// -------- weight pack: split fp32 W into hi/lo bf16, MFMA-B-fragment order ----
// chunk index ct = (kt*NCOL + n)*4 + g ; element j of chunk holds k = kt*32+g*8+j,
// col n (n<FOUT -> Wl col n ; else Wr col n-FOUT). Lane (kt,n,g) reads chunk as 16B.
template <int FOUT>
__global__ void k_pack(const float* __restrict__ Wl, const float* __restrict__ Wr,
                       ushort* __restrict__ hi, ushort* __restrict__ lo) {
  constexpr int NCOL = 2 * FOUT;
  constexpr int NCHUNK = 4 * NCOL * 4;
  int ct = blockIdx.x * 256 + threadIdx.x;
  if (ct >= NCHUNK) return;
  const int g = ct & 3;
  const int nn = (ct >> 2) % NCOL;
  const int kt = ct / (4 * NCOL);
  uint hw[4], lw[4];
#pragma unroll
  for (int w = 0; w < 4; ++w) {
    uint h2[2], l2[2];
#pragma unroll
    for (int t = 0; t < 2; ++t) {
      int j = 2 * w + t;
      int k = kt * 32 + g * 8 + j;
      float v = (nn < FOUT) ? Wl[k * FOUT + nn] : Wr[k * FOUT + (nn - FOUT)];
      uint u = __float_as_uint(v);
      uint h = u >> 16;
      float r = v - __uint_as_float(h << 16);
      uint l = __float_as_uint(r) >> 16;
      h2[t] = h; l2[t] = l;
    }
    hw[w] = h2[0] | (h2[1] << 16);
    lw[w] = l2[0] | (l2[1] << 16);
  }
  ((uint4*)hi)[ct] = make_uint4(hw[0], hw[1], hw[2], hw[3]);
  ((uint4*)lo)[ct] = make_uint4(lw[0], lw[1], lw[2], lw[3]);
}

// -------- split-bf16 MFMA dual GEMM: Z = hin@Wl ; R = hin@Wr + b --------
// Block: 32 rows x NCOL cols, 4 waves each owning NCOL/4 cols.
// A staged in LDS as hi/lo bf16 rows with slot^=(row&7) XOR swizzle (<=2-way).
// acc += Ahi*Bhi + Alo*Bhi + Ahi*Blo  (3x mfma_f32_16x16x32_bf16 per tile).
template <int FOUT>
__global__ __launch_bounds__(256) void k_gemm2(const float* __restrict__ hin,
                                               const ushort* __restrict__ Whi,
                                               const ushort* __restrict__ Wlo,
                                               const float* __restrict__ bias,
                                               float* __restrict__ Z,
                                               float* __restrict__ R, int n) {
  constexpr int NCOL = 2 * FOUT;
  constexpr int NT = NCOL / 64;  // n-tiles per wave (4 for FOUT=128, 2 for 64)
  constexpr int MT = 2;          // m-tiles (32 rows)
  __shared__ uint4 sA[2][32 * 16];  // [hi/lo][row][slot] 16B slots

  const int tid = threadIdx.x;
  const int lane = tid & 63;
  const int wave = tid >> 6;
  const int row0 = blockIdx.x * 32;

  // ---- stage 32x128 fp32 -> hi/lo bf16 in LDS ----
  {
    const int srow = tid >> 3;  // 0..31
    const int kc = tid & 7;     // 16-float chunk
    float4 f4[4];
    int g = row0 + srow;
    if (g < n) {
      const float4* hp = (const float4*)(hin + (size_t)g * 128 + kc * 16);
      f4[0] = hp[0]; f4[1] = hp[1]; f4[2] = hp[2]; f4[3] = hp[3];
    } else {
      f4[0] = f4[1] = f4[2] = f4[3] = make_float4(0.f, 0.f, 0.f, 0.f);
    }
    const float* fp = (const float*)f4;
#pragma unroll
    for (int b = 0; b < 2; ++b) {
      uint hw[4], lw[4];
#pragma unroll
      for (int w = 0; w < 4; ++w) {
        float a0 = fp[b * 8 + 2 * w], a1 = fp[b * 8 + 2 * w + 1];
        uint u0 = __float_as_uint(a0), u1 = __float_as_uint(a1);
        uint h0 = u0 >> 16, h1 = u1 >> 16;
        float r0 = a0 - __uint_as_float(h0 << 16);
        float r1 = a1 - __uint_as_float(h1 << 16);
        uint l0 = __float_as_uint(r0) >> 16, l1 = __float_as_uint(r1) >> 16;
        hw[w] = h0 | (h1 << 16);
        lw[w] = l0 | (l1 << 16);
      }
      int slot = (kc * 2 + b) ^ (srow & 7);
      sA[0][srow * 16 + slot] = make_uint4(hw[0], hw[1], hw[2], hw[3]);
      sA[1][srow * 16 + slot] = make_uint4(lw[0], lw[1], lw[2], lw[3]);
    }
  }
  __syncthreads();

  const int n0 = wave * (NCOL / 4);
  const int g16 = lane >> 4;   // k-group 0..3
  const int l16 = lane & 15;

  f32x4 acc[MT][NT];
#pragma unroll
  for (int mt = 0; mt < MT; ++mt)
#pragma unroll
    for (int nt = 0; nt < NT; ++nt) acc[mt][nt] = (f32x4)(0.f);

#pragma unroll
  for (int kt = 0; kt < 4; ++kt) {
    short8 ahi[MT], alo[MT];
#pragma unroll
    for (int mt = 0; mt < MT; ++mt) {
      int row = mt * 16 + l16;
      int slot = (kt * 4 + g16) ^ (row & 7);
      ahi[mt] = *(const short8*)&sA[0][row * 16 + slot];
      alo[mt] = *(const short8*)&sA[1][row * 16 + slot];
    }
    short8 bh[NT];
#pragma unroll
    for (int nt = 0; nt < NT; ++nt) {
      size_t chunk = (size_t)(kt * NCOL + n0 + nt * 16 + l16) * 4 + g16;
      bh[nt] = *(const short8*)(Whi + chunk * 8);
    }
#pragma unroll
    for (int mt = 0; mt < MT; ++mt)
#pragma unroll
      for (int nt = 0; nt < NT; ++nt)
        acc[mt][nt] = __builtin_amdgcn_mfma_f32_16x16x32_bf16(ahi[mt], bh[nt], acc[mt][nt], 0, 0, 0);
#pragma unroll
    for (int mt = 0; mt < MT; ++mt)
#pragma unroll
      for (int nt = 0; nt < NT; ++nt)
        acc[mt][nt] = __builtin_amdgcn_mfma_f32_16x16x32_bf16(alo[mt], bh[nt], acc[mt][nt], 0, 0, 0);
    short8 bl[NT];
#pragma unroll
    for (int nt = 0; nt < NT; ++nt) {
      size_t chunk = (size_t)(kt * NCOL + n0 + nt * 16 + l16) * 4 + g16;
      bl[nt] = *(const short8*)(Wlo + chunk * 8);
    }
#pragma unroll
    for (int mt = 0; mt < MT; ++mt)
#pragma unroll
      for (int nt = 0; nt < NT; ++nt)
        acc[mt][nt] = __builtin_amdgcn_mfma_f32_16x16x32_bf16(ahi[mt], bl[nt], acc[mt][nt], 0, 0, 0);
  }

  // ---- epilogue: C/D layout col=lane&15, row=(lane>>4)*4+j ----
#pragma unroll
  for (int nt = 0; nt < NT; ++nt) {
    int col = n0 + nt * 16 + l16;
    bool isR = col >= FOUT;
    int cw = isR ? col - FOUT : col;
    float* base = isR ? R : Z;
    float badd = isR ? bias[cw] : 0.f;
#pragma unroll
    for (int mt = 0; mt < MT; ++mt) {
#pragma unroll
      for (int j = 0; j < 4; ++j) {
        int row = row0 + mt * 16 + g16 * 4 + j;
        if (row < n) base[(size_t)row * FOUT + cw] = acc[mt][nt][j] + badd;
      }
    }
  }
}

// -------- CSR mean-aggregation + epilogue: out = act(mean(Z)*inv + R) --------
template <int FOUT, bool RELU>
__global__ __launch_bounds__(256) void k_agg2(const float* __restrict__ Z,
                                              const float* __restrict__ R,
                                              const int* __restrict__ row_ptr,
                                              const int* __restrict__ csr_src,
                                              const float* __restrict__ inv,
                                              float* __restrict__ outp, int n) {
  constexpr int FL = FOUT / 4;  // feature lanes (32 or 16)
  constexpr int EG = 64 / FL;   // edge groups per wave (2 or 4)
  const int lane = threadIdx.x & 63;
  const int node = blockIdx.x * 4 + (threadIdx.x >> 6);
  if (node >= n) return;
  const int c = lane % FL;
  const int eg = lane / FL;

  const int e0 = row_ptr[node];
  const int m = row_ptr[node + 1] - e0;  // wave-uniform
  const float4* Z4 = (const float4*)Z;

  float4 acc = make_float4(0.f, 0.f, 0.f, 0.f);
  int t = eg;
  while (t < m) {
    int ss[4];
#pragma unroll
    for (int j = 0; j < 4; ++j) {
      int tj = t + j * EG;
      int tc = (tj < m) ? tj : (m - 1);  // clamped: always valid
      ss[j] = csr_src[e0 + tc];
    }
    float4 z[4];
#pragma unroll
    for (int j = 0; j < 4; ++j) z[j] = Z4[(size_t)ss[j] * FL + c];
#pragma unroll
    for (int j = 0; j < 4; ++j) {
      if (t + j * EG < m) {
        acc.x += z[j].x; acc.y += z[j].y; acc.z += z[j].z; acc.w += z[j].w;
      }
    }
    t += 4 * EG;
  }

#pragma unroll
  for (int off = FL; off < 64; off <<= 1) {
    acc.x += __shfl_xor(acc.x, off, 64);
    acc.y += __shfl_xor(acc.y, off, 64);
    acc.z += __shfl_xor(acc.z, off, 64);
    acc.w += __shfl_xor(acc.w, off, 64);
  }

  if (eg == 0) {
    const float iv = inv[node];
    float4 r = ((const float4*)R)[(size_t)node * FL + c];
    float4 o;
    o.x = fmaf(acc.x, iv, r.x);
    o.y = fmaf(acc.y, iv, r.y);
    o.z = fmaf(acc.z, iv, r.z);
    o.w = fmaf(acc.w, iv, r.w);
    if (RELU) {
      o.x = fmaxf(o.x, 0.f); o.y = fmaxf(o.y, 0.f);
      o.z = fmaxf(o.z, 0.f); o.w = fmaxf(o.w, 0.f);
    }
    *(float4*)(outp + (size_t)node * FOUT + c * 4) = o;
  }
}

// ---------------- launch ----------------

extern "C" void kernel_launch(void* const* d_in, const int* in_sizes, int n_in,
                              void* d_out, int out_size, void* d_ws, size_t ws_size,
                              hipStream_t stream) {
  const float* x   = (const float*)d_in[0];
  const int*   ei  = (const int*)d_in[1];
  const float* Wl0 = (const float*)d_in[2];
  const float* bl0 = (const float*)d_in[3];
  const float* Wr0 = (const float*)d_in[4];
  const float* Wl1 = (const float*)d_in[5];
  const float* bl1 = (const float*)d_in[6];
  const float* Wr1 = (const float*)d_in[7];
  const float* Wl2 = (const float*)d_in[8];
  const float* bl2 = (const float*)d_in[9];
  const float* Wr2 = (const float*)d_in[10];
  float* out = (float*)d_out;

  const int N = in_sizes[0] / 128;
  const int E = in_sizes[1] / 2;
  const int* src = ei;
  const int* dst = ei + E;

  char* w = (char*)d_ws;
  auto alloc = [&](size_t bytes) {
    char* p = w;
    w += (bytes + 255) & ~(size_t)255;
    return p;
  };
  int*    cnt     = (int*)alloc((size_t)N * 4);
  int*    row_ptr = (int*)alloc((size_t)(N + 1) * 4);
  int*    cursor  = (int*)alloc((size_t)N * 4);
  int*    csr_src = (int*)alloc((size_t)E * 4 + 256);
  float*  inv     = (float*)alloc((size_t)N * 4);
  int*    partial = (int*)alloc((size_t)ceil_div(N, SCAN_CHUNK) * 4 + 256);
  ushort* Whi0    = (ushort*)alloc((size_t)4 * 256 * 4 * 16);
  ushort* Wlo0    = (ushort*)alloc((size_t)4 * 256 * 4 * 16);
  ushort* Whi1    = (ushort*)alloc((size_t)4 * 256 * 4 * 16);
  ushort* Wlo1    = (ushort*)alloc((size_t)4 * 256 * 4 * 16);
  ushort* Whi2    = (ushort*)alloc((size_t)4 * 128 * 4 * 16);
  ushort* Wlo2    = (ushort*)alloc((size_t)4 * 128 * 4 * 16);
  float*  BZ      = (float*)alloc((size_t)N * 128 * 4);
  float*  BR      = (float*)alloc((size_t)N * 128 * 4);
  float*  B0      = (float*)alloc((size_t)N * 128 * 4);
  (void)ws_size; (void)n_in; (void)out_size;

  const int P = ceil_div(N, SCAN_CHUNK);

  // ---- weight packs (independent of graph/data flow) ----
  k_pack<128><<<16, 256, 0, stream>>>(Wl0, Wr0, Whi0, Wlo0);
  k_pack<128><<<16, 256, 0, stream>>>(Wl1, Wr1, Whi1, Wlo1);
  k_pack<64><<<8, 256, 0, stream>>>(Wl2, Wr2, Whi2, Wlo2);

  // ---- CSR build ----
  k_zero_int<<<ceil_div(N, 256), 256, 0, stream>>>(cnt, N);
  k_count<<<ceil_div(E, 256), 256, 0, stream>>>(dst, cnt, E);
  k_blocksum<<<P, SCAN_BS, 0, stream>>>(cnt, partial, N);
  k_scan_partials<<<1, 256, 0, stream>>>(partial, P, row_ptr, N);
  k_scatter<<<P, SCAN_BS, 0, stream>>>(cnt, partial, row_ptr, cursor, inv, N);
  k_build_csr<<<ceil_div(E, 256), 256, 0, stream>>>(src, dst, cursor, csr_src, E);

  // ---- layer 0: x -> (Z,R) -> H1 (B0) ----
  k_gemm2<128><<<ceil_div(N, 32), 256, 0, stream>>>(x, Whi0, Wlo0, bl0, BZ, BR, N);
  k_agg2<128, true><<<ceil_div(N, 4), 256, 0, stream>>>(BZ, BR, row_ptr, csr_src, inv, B0, N);

  // ---- layer 1: B0 -> (Z,R) -> H2 (B0) ----
  k_gemm2<128><<<ceil_div(N, 32), 256, 0, stream>>>(B0, Whi1, Wlo1, bl1, BZ, BR, N);
  k_agg2<128, true><<<ceil_div(N, 4), 256, 0, stream>>>(BZ, BR, row_ptr, csr_src, inv, B0, N);

  // ---- layer 2: B0 -> (Z,R) 64-wide -> out ----
  k_gemm2<64><<<ceil_div(N, 32), 256, 0, stream>>>(B0, Whi2, Wlo2, bl2, BZ, BR, N);
  k_agg2<64, false><<<ceil_div(N, 4), 256, 0, stream>>>(BZ, BR, row_ptr, csr_src, inv, out, N);
}

// Round 6
// 269.440 us; speedup vs baseline: 1.9506x; 1.2500x over previous
//
#include <hip/hip_runtime.h>

static inline int ceil_div(int a, int b) { return (a + b - 1) / b; }

typedef __attribute__((ext_vector_type(8))) short short8;   // 8 bf16 = 4 VGPR
typedef __attribute__((ext_vector_type(4))) float f32x4;

__device__ __forceinline__ ushort bf16_rne(float v) {
  uint u = __float_as_uint(v);
  return (ushort)((u + 0x7FFFu + ((u >> 16) & 1u)) >> 16);
}

// ---------------- CSR build ----------------

__global__ void k_zero_int(int* __restrict__ p, int n) {
  int i = blockIdx.x * blockDim.x + threadIdx.x;
  if (i < n) p[i] = 0;
}

__global__ void k_count(const int* __restrict__ dst, int* __restrict__ cnt, int e) {
  int i = blockIdx.x * blockDim.x + threadIdx.x;
  if (i < e) atomicAdd(&cnt[dst[i]], 1);
}

#define SCAN_BS 256
#define SCAN_VPT 4
#define SCAN_CHUNK (SCAN_BS * SCAN_VPT)

__global__ __launch_bounds__(SCAN_BS) void k_blocksum(const int* __restrict__ cnt,
                                                      int* __restrict__ partial, int n) {
  __shared__ int s[SCAN_BS / 64];
  const int tid = threadIdx.x;
  const int base = blockIdx.x * SCAN_CHUNK;
  int sum = 0;
#pragma unroll
  for (int j = 0; j < SCAN_VPT; ++j) {
    int i = base + tid + j * SCAN_BS;
    if (i < n) sum += cnt[i];
  }
#pragma unroll
  for (int off = 32; off > 0; off >>= 1) sum += __shfl_down(sum, off, 64);
  if ((tid & 63) == 0) s[tid >> 6] = sum;
  __syncthreads();
  if (tid == 0) {
    int t = 0;
#pragma unroll
    for (int w = 0; w < SCAN_BS / 64; ++w) t += s[w];
    partial[blockIdx.x] = t;
  }
}

__global__ __launch_bounds__(256) void k_scan_partials(int* __restrict__ partial, int p,
                                                       int* __restrict__ row_ptr, int n_nodes) {
  __shared__ int s[256];
  const int tid = threadIdx.x;
  int carry = 0;
  for (int base = 0; base < p; base += 256) {
    int i = base + tid;
    int v = (i < p) ? partial[i] : 0;
    s[tid] = v;
    __syncthreads();
    for (int off = 1; off < 256; off <<= 1) {
      int t = (tid >= off) ? s[tid - off] : 0;
      __syncthreads();
      s[tid] += t;
      __syncthreads();
    }
    if (i < p) partial[i] = carry + s[tid] - v;  // exclusive
    int tot = s[255];
    __syncthreads();
    carry += tot;
  }
  if (tid == 0) row_ptr[n_nodes] = carry;
}

__global__ __launch_bounds__(SCAN_BS) void k_scatter(const int* __restrict__ cnt,
                                                     const int* __restrict__ partial,
                                                     int* __restrict__ row_ptr,
                                                     int* __restrict__ cursor,
                                                     float* __restrict__ inv, int n) {
  __shared__ int s[SCAN_BS];
  const int tid = threadIdx.x;
  const int base = blockIdx.x * SCAN_CHUNK;
  const int i0 = base + tid * SCAN_VPT;
  int v[SCAN_VPT];
  int cv[SCAN_VPT];
  int sum = 0;
#pragma unroll
  for (int j = 0; j < SCAN_VPT; ++j) {
    int i = i0 + j;
    int c = (i < n) ? cnt[i] : 0;
    cv[j] = c;
    v[j] = sum;
    sum += c;
  }
  s[tid] = sum;
  __syncthreads();
  for (int off = 1; off < SCAN_BS; off <<= 1) {
    int t = (tid >= off) ? s[tid - off] : 0;
    __syncthreads();
    s[tid] += t;
    __syncthreads();
  }
  const int excl = partial[blockIdx.x] + s[tid] - sum;
#pragma unroll
  for (int j = 0; j < SCAN_VPT; ++j) {
    int i = i0 + j;
    if (i < n) {
      int e = excl + v[j];
      row_ptr[i] = e;
      cursor[i] = e;
      inv[i] = 1.0f / (float)(cv[j] > 1 ? cv[j] : 1);
    }
  }
}

__global__ void k_build_csr(const int* __restrict__ src, const int* __restrict__ dst,
                            int* __restrict__ cursor, int* __restrict__ csr_src, int e) {
  int i = blockIdx.x * blockDim.x + threadIdx.x;
  if (i < e) {
    int pos = atomicAdd(&cursor[dst[i]], 1);
    csr_src[pos] = src[i];
  }
}

// -------- weight pack: split fp32 W into hi/lo bf16, MFMA-B-fragment order ----
template <int FOUT>
__global__ void k_pack(const float* __restrict__ Wl, const float* __restrict__ Wr,
                       ushort* __restrict__ hi, ushort* __restrict__ lo) {
  constexpr int NCOL = 2 * FOUT;
  constexpr int NCHUNK = 4 * NCOL * 4;
  int ct = blockIdx.x * 256 + threadIdx.x;
  if (ct >= NCHUNK) return;
  const int g = ct & 3;
  const int nn = (ct >> 2) % NCOL;
  const int kt = ct / (4 * NCOL);
  uint hw[4], lw[4];
#pragma unroll
  for (int w = 0; w < 4; ++w) {
    uint h2[2], l2[2];
#pragma unroll
    for (int t = 0; t < 2; ++t) {
      int j = 2 * w + t;
      int k = kt * 32 + g * 8 + j;
      float v = (nn < FOUT) ? Wl[k * FOUT + nn] : Wr[k * FOUT + (nn - FOUT)];
      uint u = __float_as_uint(v);
      uint h = u >> 16;
      float r = v - __uint_as_float(h << 16);
      uint l = __float_as_uint(r) >> 16;
      h2[t] = h; l2[t] = l;
    }
    hw[w] = h2[0] | (h2[1] << 16);
    lw[w] = l2[0] | (l2[1] << 16);
  }
  ((uint4*)hi)[ct] = make_uint4(hw[0], hw[1], hw[2], hw[3]);
  ((uint4*)lo)[ct] = make_uint4(lw[0], lw[1], lw[2], lw[3]);
}

// -------- split-bf16 MFMA dual GEMM: Z(bf16) = hin@Wl ; R(fp32) = hin@Wr + b ---
template <int FOUT>
__global__ __launch_bounds__(256) void k_gemm2(const float* __restrict__ hin,
                                               const ushort* __restrict__ Whi,
                                               const ushort* __restrict__ Wlo,
                                               const float* __restrict__ bias,
                                               ushort* __restrict__ Zb,
                                               float* __restrict__ R, int n) {
  constexpr int NCOL = 2 * FOUT;
  constexpr int NT = NCOL / 64;  // n-tiles per wave (4 for FOUT=128, 2 for 64)
  constexpr int MT = 2;          // m-tiles (32 rows)
  __shared__ uint4 sA[2][32 * 16];  // [hi/lo][row][slot] 16B slots

  const int tid = threadIdx.x;
  const int lane = tid & 63;
  const int wave = tid >> 6;
  const int row0 = blockIdx.x * 32;

  // ---- stage 32x128 fp32 -> hi/lo bf16 in LDS ----
  {
    const int srow = tid >> 3;  // 0..31
    const int kc = tid & 7;     // 16-float chunk
    float4 f4[4];
    int g = row0 + srow;
    if (g < n) {
      const float4* hp = (const float4*)(hin + (size_t)g * 128 + kc * 16);
      f4[0] = hp[0]; f4[1] = hp[1]; f4[2] = hp[2]; f4[3] = hp[3];
    } else {
      f4[0] = f4[1] = f4[2] = f4[3] = make_float4(0.f, 0.f, 0.f, 0.f);
    }
    const float* fp = (const float*)f4;
#pragma unroll
    for (int b = 0; b < 2; ++b) {
      uint hw[4], lw[4];
#pragma unroll
      for (int w = 0; w < 4; ++w) {
        float a0 = fp[b * 8 + 2 * w], a1 = fp[b * 8 + 2 * w + 1];
        uint u0 = __float_as_uint(a0), u1 = __float_as_uint(a1);
        uint h0 = u0 >> 16, h1 = u1 >> 16;
        float r0 = a0 - __uint_as_float(h0 << 16);
        float r1 = a1 - __uint_as_float(h1 << 16);
        uint l0 = __float_as_uint(r0) >> 16, l1 = __float_as_uint(r1) >> 16;
        hw[w] = h0 | (h1 << 16);
        lw[w] = l0 | (l1 << 16);
      }
      int slot = (kc * 2 + b) ^ (srow & 7);
      sA[0][srow * 16 + slot] = make_uint4(hw[0], hw[1], hw[2], hw[3]);
      sA[1][srow * 16 + slot] = make_uint4(lw[0], lw[1], lw[2], lw[3]);
    }
  }
  __syncthreads();

  const int n0 = wave * (NCOL / 4);
  const int g16 = lane >> 4;   // k-group 0..3
  const int l16 = lane & 15;

  f32x4 acc[MT][NT];
#pragma unroll
  for (int mt = 0; mt < MT; ++mt)
#pragma unroll
    for (int nt = 0; nt < NT; ++nt) acc[mt][nt] = (f32x4)(0.f);

#pragma unroll
  for (int kt = 0; kt < 4; ++kt) {
    short8 ahi[MT], alo[MT];
#pragma unroll
    for (int mt = 0; mt < MT; ++mt) {
      int row = mt * 16 + l16;
      int slot = (kt * 4 + g16) ^ (row & 7);
      ahi[mt] = *(const short8*)&sA[0][row * 16 + slot];
      alo[mt] = *(const short8*)&sA[1][row * 16 + slot];
    }
    short8 bh[NT];
#pragma unroll
    for (int nt = 0; nt < NT; ++nt) {
      size_t chunk = (size_t)(kt * NCOL + n0 + nt * 16 + l16) * 4 + g16;
      bh[nt] = *(const short8*)(Whi + chunk * 8);
    }
#pragma unroll
    for (int mt = 0; mt < MT; ++mt)
#pragma unroll
      for (int nt = 0; nt < NT; ++nt)
        acc[mt][nt] = __builtin_amdgcn_mfma_f32_16x16x32_bf16(ahi[mt], bh[nt], acc[mt][nt], 0, 0, 0);
#pragma unroll
    for (int mt = 0; mt < MT; ++mt)
#pragma unroll
      for (int nt = 0; nt < NT; ++nt)
        acc[mt][nt] = __builtin_amdgcn_mfma_f32_16x16x32_bf16(alo[mt], bh[nt], acc[mt][nt], 0, 0, 0);
    short8 bl[NT];
#pragma unroll
    for (int nt = 0; nt < NT; ++nt) {
      size_t chunk = (size_t)(kt * NCOL + n0 + nt * 16 + l16) * 4 + g16;
      bl[nt] = *(const short8*)(Wlo + chunk * 8);
    }
#pragma unroll
    for (int mt = 0; mt < MT; ++mt)
#pragma unroll
      for (int nt = 0; nt < NT; ++nt)
        acc[mt][nt] = __builtin_amdgcn_mfma_f32_16x16x32_bf16(ahi[mt], bl[nt], acc[mt][nt], 0, 0, 0);
  }

  // ---- epilogue: C/D layout col=lane&15, row=(lane>>4)*4+j ----
#pragma unroll
  for (int nt = 0; nt < NT; ++nt) {
    int col = n0 + nt * 16 + l16;
    bool isR = col >= FOUT;
    int cw = isR ? col - FOUT : col;
    float badd = isR ? bias[cw] : 0.f;
#pragma unroll
    for (int mt = 0; mt < MT; ++mt) {
#pragma unroll
      for (int j = 0; j < 4; ++j) {
        int row = row0 + mt * 16 + g16 * 4 + j;
        if (row < n) {
          float v = acc[mt][nt][j] + badd;
          if (isR) R[(size_t)row * FOUT + cw] = v;
          else Zb[(size_t)row * FOUT + cw] = bf16_rne(v);
        }
      }
    }
  }
}

// -------- CSR mean-aggregation + epilogue: out = act(mean(Zb)*inv + R) --------
// Zb is bf16: FL lanes x 16B (8 bf16) per row; EG edge groups; 4-deep unroll ->
// 16 (F=128) / 32 (F=64) edges in flight per wave.
template <int FOUT, bool RELU>
__global__ __launch_bounds__(256) void k_agg2(const ushort* __restrict__ Zb,
                                              const float* __restrict__ R,
                                              const int* __restrict__ row_ptr,
                                              const int* __restrict__ csr_src,
                                              const float* __restrict__ inv,
                                              float* __restrict__ outp, int n) {
  constexpr int FL = FOUT / 8;  // lanes per row (16 or 8)
  constexpr int EG = 64 / FL;   // edge groups per wave (4 or 8)
  const int lane = threadIdx.x & 63;
  const int node = blockIdx.x * 4 + (threadIdx.x >> 6);
  if (node >= n) return;
  const int c = lane % FL;
  const int eg = lane / FL;

  const int e0 = row_ptr[node];
  const int m = row_ptr[node + 1] - e0;  // wave-uniform
  const uint4* Z4 = (const uint4*)Zb;    // 16B = 8 bf16

  float acc[8];
#pragma unroll
  for (int k = 0; k < 8; ++k) acc[k] = 0.f;

  int t = eg;
  while (t < m) {
    int ss[4];
#pragma unroll
    for (int j = 0; j < 4; ++j) {
      int tj = t + j * EG;
      int tc = (tj < m) ? tj : (m - 1);  // clamped: always valid
      ss[j] = csr_src[e0 + tc];
    }
    uint4 z[4];
#pragma unroll
    for (int j = 0; j < 4; ++j) z[j] = Z4[(size_t)ss[j] * FL + c];
#pragma unroll
    for (int j = 0; j < 4; ++j) {
      if (t + j * EG < m) {
        const uint* zw = (const uint*)&z[j];
#pragma unroll
        for (int w = 0; w < 4; ++w) {
          acc[2 * w]     += __uint_as_float(zw[w] << 16);
          acc[2 * w + 1] += __uint_as_float(zw[w] & 0xFFFF0000u);
        }
      }
    }
    t += 4 * EG;
  }

#pragma unroll
  for (int off = FL; off < 64; off <<= 1) {
#pragma unroll
    for (int k = 0; k < 8; ++k) acc[k] += __shfl_xor(acc[k], off, 64);
  }

  if (eg == 0) {
    const float iv = inv[node];
    const float4* Rp = (const float4*)(R + (size_t)node * FOUT + c * 8);
    float4 r0 = Rp[0], r1 = Rp[1];
    float4 o0, o1;
    o0.x = fmaf(acc[0], iv, r0.x);
    o0.y = fmaf(acc[1], iv, r0.y);
    o0.z = fmaf(acc[2], iv, r0.z);
    o0.w = fmaf(acc[3], iv, r0.w);
    o1.x = fmaf(acc[4], iv, r1.x);
    o1.y = fmaf(acc[5], iv, r1.y);
    o1.z = fmaf(acc[6], iv, r1.z);
    o1.w = fmaf(acc[7], iv, r1.w);
    if (RELU) {
      o0.x = fmaxf(o0.x, 0.f); o0.y = fmaxf(o0.y, 0.f);
      o0.z = fmaxf(o0.z, 0.f); o0.w = fmaxf(o0.w, 0.f);
      o1.x = fmaxf(o1.x, 0.f); o1.y = fmaxf(o1.y, 0.f);
      o1.z = fmaxf(o1.z, 0.f); o1.w = fmaxf(o1.w, 0.f);
    }
    float4* op = (float4*)(outp + (size_t)node * FOUT + c * 8);
    op[0] = o0;
    op[1] = o1;
  }
}

// ---------------- launch ----------------

extern "C" void kernel_launch(void* const* d_in, const int* in_sizes, int n_in,
                              void* d_out, int out_size, void* d_ws, size_t ws_size,
                              hipStream_t stream) {
  const float* x   = (const float*)d_in[0];
  const int*   ei  = (const int*)d_in[1];
  const float* Wl0 = (const float*)d_in[2];
  const float* bl0 = (const float*)d_in[3];
  const float* Wr0 = (const float*)d_in[4];
  const float* Wl1 = (const float*)d_in[5];
  const float* bl1 = (const float*)d_in[6];
  const float* Wr1 = (const float*)d_in[7];
  const float* Wl2 = (const float*)d_in[8];
  const float* bl2 = (const float*)d_in[9];
  const float* Wr2 = (const float*)d_in[10];
  float* out = (float*)d_out;

  const int N = in_sizes[0] / 128;
  const int E = in_sizes[1] / 2;
  const int* src = ei;
  const int* dst = ei + E;

  char* w = (char*)d_ws;
  auto alloc = [&](size_t bytes) {
    char* p = w;
    w += (bytes + 255) & ~(size_t)255;
    return p;
  };
  int*    cnt     = (int*)alloc((size_t)N * 4);
  int*    row_ptr = (int*)alloc((size_t)(N + 1) * 4);
  int*    cursor  = (int*)alloc((size_t)N * 4);
  int*    csr_src = (int*)alloc((size_t)E * 4 + 256);
  float*  inv     = (float*)alloc((size_t)N * 4);
  int*    partial = (int*)alloc((size_t)ceil_div(N, SCAN_CHUNK) * 4 + 256);
  ushort* Whi0    = (ushort*)alloc((size_t)4 * 256 * 4 * 16);
  ushort* Wlo0    = (ushort*)alloc((size_t)4 * 256 * 4 * 16);
  ushort* Whi1    = (ushort*)alloc((size_t)4 * 256 * 4 * 16);
  ushort* Wlo1    = (ushort*)alloc((size_t)4 * 256 * 4 * 16);
  ushort* Whi2    = (ushort*)alloc((size_t)4 * 128 * 4 * 16);
  ushort* Wlo2    = (ushort*)alloc((size_t)4 * 128 * 4 * 16);
  ushort* BZ      = (ushort*)alloc((size_t)N * 128 * 2);
  float*  BR      = (float*)alloc((size_t)N * 128 * 4);
  float*  B0      = (float*)alloc((size_t)N * 128 * 4);
  (void)ws_size; (void)n_in; (void)out_size;

  const int P = ceil_div(N, SCAN_CHUNK);

  // ---- weight packs ----
  k_pack<128><<<16, 256, 0, stream>>>(Wl0, Wr0, Whi0, Wlo0);
  k_pack<128><<<16, 256, 0, stream>>>(Wl1, Wr1, Whi1, Wlo1);
  k_pack<64><<<8, 256, 0, stream>>>(Wl2, Wr2, Whi2, Wlo2);

  // ---- CSR build ----
  k_zero_int<<<ceil_div(N, 256), 256, 0, stream>>>(cnt, N);
  k_count<<<ceil_div(E, 256), 256, 0, stream>>>(dst, cnt, E);
  k_blocksum<<<P, SCAN_BS, 0, stream>>>(cnt, partial, N);
  k_scan_partials<<<1, 256, 0, stream>>>(partial, P, row_ptr, N);
  k_scatter<<<P, SCAN_BS, 0, stream>>>(cnt, partial, row_ptr, cursor, inv, N);
  k_build_csr<<<ceil_div(E, 256), 256, 0, stream>>>(src, dst, cursor, csr_src, E);

  // ---- layer 0: x -> (Zb,R) -> H1 (B0) ----
  k_gemm2<128><<<ceil_div(N, 32), 256, 0, stream>>>(x, Whi0, Wlo0, bl0, BZ, BR, N);
  k_agg2<128, true><<<ceil_div(N, 4), 256, 0, stream>>>(BZ, BR, row_ptr, csr_src, inv, B0, N);

  // ---- layer 1: B0 -> (Zb,R) -> H2 (B0) ----
  k_gemm2<128><<<ceil_div(N, 32), 256, 0, stream>>>(B0, Whi1, Wlo1, bl1, BZ, BR, N);
  k_agg2<128, true><<<ceil_div(N, 4), 256, 0, stream>>>(BZ, BR, row_ptr, csr_src, inv, B0, N);

  // ---- layer 2: B0 -> (Zb,R) 64-wide -> out ----
  k_gemm2<64><<<ceil_div(N, 32), 256, 0, stream>>>(B0, Whi2, Wlo2, bl2, BZ, BR, N);
  k_agg2<64, false><<<ceil_div(N, 4), 256, 0, stream>>>(BZ, BR, row_ptr, csr_src, inv, out, N);
}

// Round 7
// 236.909 us; speedup vs baseline: 2.2184x; 1.1373x over previous
//
#include <hip/hip_runtime.h>

static inline int ceil_div(int a, int b) { return (a + b - 1) / b; }

typedef __attribute__((ext_vector_type(8))) short short8;   // 8 bf16 = 4 VGPR
typedef __attribute__((ext_vector_type(4))) float f32x4;

__device__ __forceinline__ ushort bf16_rne(float v) {
  uint u = __float_as_uint(v);
  return (ushort)((u + 0x7FFFu + ((u >> 16) & 1u)) >> 16);
}

// ---------------- CSR build ----------------

__global__ void k_zero_int(int* __restrict__ p, int n) {
  int i = blockIdx.x * blockDim.x + threadIdx.x;
  if (i < n) p[i] = 0;
}

// histogram + per-edge rank (coalesced int4 loads/stores, 4 atomics in flight)
__global__ void k_count_rank(const int* __restrict__ dst, int* __restrict__ cnt,
                             int* __restrict__ rank, int e) {
  int i0 = (blockIdx.x * blockDim.x + threadIdx.x) * 4;
  if (i0 >= e) return;
  int d[4], r[4];
  if (i0 + 3 < e) {
    int4 dv = *(const int4*)(dst + i0);
    d[0] = dv.x; d[1] = dv.y; d[2] = dv.z; d[3] = dv.w;
  } else {
#pragma unroll
    for (int j = 0; j < 4; ++j) d[j] = (i0 + j < e) ? dst[i0 + j] : 0;
  }
#pragma unroll
  for (int j = 0; j < 4; ++j)
    if (i0 + j < e) r[j] = atomicAdd(&cnt[d[j]], 1);
  if (i0 + 3 < e) {
    *(int4*)(rank + i0) = make_int4(r[0], r[1], r[2], r[3]);
  } else {
#pragma unroll
    for (int j = 0; j < 4; ++j)
      if (i0 + j < e) rank[i0 + j] = r[j];
  }
}

#define SCAN_BS 256
#define SCAN_VPT 4
#define SCAN_CHUNK (SCAN_BS * SCAN_VPT)

__global__ __launch_bounds__(SCAN_BS) void k_blocksum(const int* __restrict__ cnt,
                                                      int* __restrict__ partial, int n) {
  __shared__ int s[SCAN_BS / 64];
  const int tid = threadIdx.x;
  const int base = blockIdx.x * SCAN_CHUNK;
  int sum = 0;
#pragma unroll
  for (int j = 0; j < SCAN_VPT; ++j) {
    int i = base + tid + j * SCAN_BS;
    if (i < n) sum += cnt[i];
  }
#pragma unroll
  for (int off = 32; off > 0; off >>= 1) sum += __shfl_down(sum, off, 64);
  if ((tid & 63) == 0) s[tid >> 6] = sum;
  __syncthreads();
  if (tid == 0) {
    int t = 0;
#pragma unroll
    for (int w = 0; w < SCAN_BS / 64; ++w) t += s[w];
    partial[blockIdx.x] = t;
  }
}

__global__ __launch_bounds__(256) void k_scan_partials(int* __restrict__ partial, int p,
                                                       int* __restrict__ row_ptr, int n_nodes) {
  __shared__ int s[256];
  const int tid = threadIdx.x;
  int carry = 0;
  for (int base = 0; base < p; base += 256) {
    int i = base + tid;
    int v = (i < p) ? partial[i] : 0;
    s[tid] = v;
    __syncthreads();
    for (int off = 1; off < 256; off <<= 1) {
      int t = (tid >= off) ? s[tid - off] : 0;
      __syncthreads();
      s[tid] += t;
      __syncthreads();
    }
    if (i < p) partial[i] = carry + s[tid] - v;  // exclusive
    int tot = s[255];
    __syncthreads();
    carry += tot;
  }
  if (tid == 0) row_ptr[n_nodes] = carry;
}

__global__ __launch_bounds__(SCAN_BS) void k_scatter(const int* __restrict__ cnt,
                                                     const int* __restrict__ partial,
                                                     int* __restrict__ row_ptr,
                                                     float* __restrict__ inv, int n) {
  __shared__ int s[SCAN_BS];
  const int tid = threadIdx.x;
  const int base = blockIdx.x * SCAN_CHUNK;
  const int i0 = base + tid * SCAN_VPT;
  int v[SCAN_VPT];
  int cv[SCAN_VPT];
  int sum = 0;
#pragma unroll
  for (int j = 0; j < SCAN_VPT; ++j) {
    int i = i0 + j;
    int c = (i < n) ? cnt[i] : 0;
    cv[j] = c;
    v[j] = sum;
    sum += c;
  }
  s[tid] = sum;
  __syncthreads();
  for (int off = 1; off < SCAN_BS; off <<= 1) {
    int t = (tid >= off) ? s[tid - off] : 0;
    __syncthreads();
    s[tid] += t;
    __syncthreads();
  }
  const int excl = partial[blockIdx.x] + s[tid] - sum;
#pragma unroll
  for (int j = 0; j < SCAN_VPT; ++j) {
    int i = i0 + j;
    if (i < n) {
      row_ptr[i] = excl + v[j];
      inv[i] = 1.0f / (float)(cv[j] > 1 ? cv[j] : 1);
    }
  }
}

// place edges: csr16[row_ptr[dst] + rank] = (ushort)src ; no atomics
__global__ void k_place(const int* __restrict__ src, const int* __restrict__ dst,
                        const int* __restrict__ rank, const int* __restrict__ row_ptr,
                        ushort* __restrict__ csr16, int e) {
  int i0 = (blockIdx.x * blockDim.x + threadIdx.x) * 4;
  if (i0 >= e) return;
  if (i0 + 3 < e) {
    int4 dv = *(const int4*)(dst + i0);
    int4 sv = *(const int4*)(src + i0);
    int4 rv = *(const int4*)(rank + i0);
    int p0 = row_ptr[dv.x], p1 = row_ptr[dv.y], p2 = row_ptr[dv.z], p3 = row_ptr[dv.w];
    csr16[p0 + rv.x] = (ushort)sv.x;
    csr16[p1 + rv.y] = (ushort)sv.y;
    csr16[p2 + rv.z] = (ushort)sv.z;
    csr16[p3 + rv.w] = (ushort)sv.w;
  } else {
#pragma unroll
    for (int j = 0; j < 4; ++j) {
      int i = i0 + j;
      if (i < e) csr16[row_ptr[dst[i]] + rank[i]] = (ushort)src[i];
    }
  }
}

// -------- weight pack: split fp32 W into hi/lo bf16, MFMA-B-fragment order ----
template <int FOUT>
__global__ void k_pack(const float* __restrict__ Wl, const float* __restrict__ Wr,
                       ushort* __restrict__ hi, ushort* __restrict__ lo) {
  constexpr int NCOL = 2 * FOUT;
  constexpr int NCHUNK = 4 * NCOL * 4;
  int ct = blockIdx.x * 256 + threadIdx.x;
  if (ct >= NCHUNK) return;
  const int g = ct & 3;
  const int nn = (ct >> 2) % NCOL;
  const int kt = ct / (4 * NCOL);
  uint hw[4], lw[4];
#pragma unroll
  for (int w = 0; w < 4; ++w) {
    uint h2[2], l2[2];
#pragma unroll
    for (int t = 0; t < 2; ++t) {
      int j = 2 * w + t;
      int k = kt * 32 + g * 8 + j;
      float v = (nn < FOUT) ? Wl[k * FOUT + nn] : Wr[k * FOUT + (nn - FOUT)];
      uint u = __float_as_uint(v);
      uint h = u >> 16;
      float r = v - __uint_as_float(h << 16);
      uint l = __float_as_uint(r) >> 16;
      h2[t] = h; l2[t] = l;
    }
    hw[w] = h2[0] | (h2[1] << 16);
    lw[w] = l2[0] | (l2[1] << 16);
  }
  ((uint4*)hi)[ct] = make_uint4(hw[0], hw[1], hw[2], hw[3]);
  ((uint4*)lo)[ct] = make_uint4(lw[0], lw[1], lw[2], lw[3]);
}

// -------- split-bf16 MFMA dual GEMM: Z(bf16) = hin@Wl ; R(fp32) = hin@Wr + b ---
template <int FOUT>
__global__ __launch_bounds__(256) void k_gemm2(const float* __restrict__ hin,
                                               const ushort* __restrict__ Whi,
                                               const ushort* __restrict__ Wlo,
                                               const float* __restrict__ bias,
                                               ushort* __restrict__ Zb,
                                               float* __restrict__ R, int n) {
  constexpr int NCOL = 2 * FOUT;
  constexpr int NT = NCOL / 64;  // n-tiles per wave (4 for FOUT=128, 2 for 64)
  constexpr int MT = 2;          // m-tiles (32 rows)
  __shared__ uint4 sA[2][32 * 16];  // [hi/lo][row][slot] 16B slots

  const int tid = threadIdx.x;
  const int lane = tid & 63;
  const int wave = tid >> 6;
  const int row0 = blockIdx.x * 32;

  // ---- stage 32x128 fp32 -> hi/lo bf16 in LDS ----
  {
    const int srow = tid >> 3;  // 0..31
    const int kc = tid & 7;     // 16-float chunk
    float4 f4[4];
    int g = row0 + srow;
    if (g < n) {
      const float4* hp = (const float4*)(hin + (size_t)g * 128 + kc * 16);
      f4[0] = hp[0]; f4[1] = hp[1]; f4[2] = hp[2]; f4[3] = hp[3];
    } else {
      f4[0] = f4[1] = f4[2] = f4[3] = make_float4(0.f, 0.f, 0.f, 0.f);
    }
    const float* fp = (const float*)f4;
#pragma unroll
    for (int b = 0; b < 2; ++b) {
      uint hw[4], lw[4];
#pragma unroll
      for (int w = 0; w < 4; ++w) {
        float a0 = fp[b * 8 + 2 * w], a1 = fp[b * 8 + 2 * w + 1];
        uint u0 = __float_as_uint(a0), u1 = __float_as_uint(a1);
        uint h0 = u0 >> 16, h1 = u1 >> 16;
        float r0 = a0 - __uint_as_float(h0 << 16);
        float r1 = a1 - __uint_as_float(h1 << 16);
        uint l0 = __float_as_uint(r0) >> 16, l1 = __float_as_uint(r1) >> 16;
        hw[w] = h0 | (h1 << 16);
        lw[w] = l0 | (l1 << 16);
      }
      int slot = (kc * 2 + b) ^ (srow & 7);
      sA[0][srow * 16 + slot] = make_uint4(hw[0], hw[1], hw[2], hw[3]);
      sA[1][srow * 16 + slot] = make_uint4(lw[0], lw[1], lw[2], lw[3]);
    }
  }
  __syncthreads();

  const int n0 = wave * (NCOL / 4);
  const int g16 = lane >> 4;   // k-group 0..3
  const int l16 = lane & 15;

  f32x4 acc[MT][NT];
#pragma unroll
  for (int mt = 0; mt < MT; ++mt)
#pragma unroll
    for (int nt = 0; nt < NT; ++nt) acc[mt][nt] = (f32x4)(0.f);

#pragma unroll
  for (int kt = 0; kt < 4; ++kt) {
    short8 ahi[MT], alo[MT];
#pragma unroll
    for (int mt = 0; mt < MT; ++mt) {
      int row = mt * 16 + l16;
      int slot = (kt * 4 + g16) ^ (row & 7);
      ahi[mt] = *(const short8*)&sA[0][row * 16 + slot];
      alo[mt] = *(const short8*)&sA[1][row * 16 + slot];
    }
    short8 bh[NT];
#pragma unroll
    for (int nt = 0; nt < NT; ++nt) {
      size_t chunk = (size_t)(kt * NCOL + n0 + nt * 16 + l16) * 4 + g16;
      bh[nt] = *(const short8*)(Whi + chunk * 8);
    }
#pragma unroll
    for (int mt = 0; mt < MT; ++mt)
#pragma unroll
      for (int nt = 0; nt < NT; ++nt)
        acc[mt][nt] = __builtin_amdgcn_mfma_f32_16x16x32_bf16(ahi[mt], bh[nt], acc[mt][nt], 0, 0, 0);
#pragma unroll
    for (int mt = 0; mt < MT; ++mt)
#pragma unroll
      for (int nt = 0; nt < NT; ++nt)
        acc[mt][nt] = __builtin_amdgcn_mfma_f32_16x16x32_bf16(alo[mt], bh[nt], acc[mt][nt], 0, 0, 0);
    short8 bl[NT];
#pragma unroll
    for (int nt = 0; nt < NT; ++nt) {
      size_t chunk = (size_t)(kt * NCOL + n0 + nt * 16 + l16) * 4 + g16;
      bl[nt] = *(const short8*)(Wlo + chunk * 8);
    }
#pragma unroll
    for (int mt = 0; mt < MT; ++mt)
#pragma unroll
      for (int nt = 0; nt < NT; ++nt)
        acc[mt][nt] = __builtin_amdgcn_mfma_f32_16x16x32_bf16(ahi[mt], bl[nt], acc[mt][nt], 0, 0, 0);
  }

  // ---- epilogue: C/D layout col=lane&15, row=(lane>>4)*4+j ----
#pragma unroll
  for (int nt = 0; nt < NT; ++nt) {
    int col = n0 + nt * 16 + l16;
    bool isR = col >= FOUT;
    int cw = isR ? col - FOUT : col;
    float badd = isR ? bias[cw] : 0.f;
#pragma unroll
    for (int mt = 0; mt < MT; ++mt) {
#pragma unroll
      for (int j = 0; j < 4; ++j) {
        int row = row0 + mt * 16 + g16 * 4 + j;
        if (row < n) {
          float v = acc[mt][nt][j] + badd;
          if (isR) R[(size_t)row * FOUT + cw] = v;
          else Zb[(size_t)row * FOUT + cw] = bf16_rne(v);
        }
      }
    }
  }
}

// -------- CSR mean-aggregation + epilogue: out = act(mean(Zb)*inv + R) --------
template <int FOUT, bool RELU>
__global__ __launch_bounds__(256) void k_agg2(const ushort* __restrict__ Zb,
                                              const float* __restrict__ R,
                                              const int* __restrict__ row_ptr,
                                              const ushort* __restrict__ csr16,
                                              const float* __restrict__ inv,
                                              float* __restrict__ outp, int n) {
  constexpr int FL = FOUT / 8;  // lanes per row (16 or 8)
  constexpr int EG = 64 / FL;   // edge groups per wave (4 or 8)
  const int lane = threadIdx.x & 63;
  const int node = blockIdx.x * 4 + (threadIdx.x >> 6);
  if (node >= n) return;
  const int c = lane % FL;
  const int eg = lane / FL;

  const int e0 = row_ptr[node];
  const int m = row_ptr[node + 1] - e0;  // wave-uniform
  const uint4* Z4 = (const uint4*)Zb;    // 16B = 8 bf16

  float acc[8];
#pragma unroll
  for (int k = 0; k < 8; ++k) acc[k] = 0.f;

  int t = eg;
  while (t < m) {
    int ss[4];
#pragma unroll
    for (int j = 0; j < 4; ++j) {
      int tj = t + j * EG;
      int tc = (tj < m) ? tj : (m - 1);  // clamped: always valid
      ss[j] = csr16[e0 + tc];
    }
    uint4 z[4];
#pragma unroll
    for (int j = 0; j < 4; ++j) z[j] = Z4[(size_t)ss[j] * FL + c];
#pragma unroll
    for (int j = 0; j < 4; ++j) {
      if (t + j * EG < m) {
        const uint* zw = (const uint*)&z[j];
#pragma unroll
        for (int w = 0; w < 4; ++w) {
          acc[2 * w]     += __uint_as_float(zw[w] << 16);
          acc[2 * w + 1] += __uint_as_float(zw[w] & 0xFFFF0000u);
        }
      }
    }
    t += 4 * EG;
  }

#pragma unroll
  for (int off = FL; off < 64; off <<= 1) {
#pragma unroll
    for (int k = 0; k < 8; ++k) acc[k] += __shfl_xor(acc[k], off, 64);
  }

  if (eg == 0) {
    const float iv = inv[node];
    const float4* Rp = (const float4*)(R + (size_t)node * FOUT + c * 8);
    float4 r0 = Rp[0], r1 = Rp[1];
    float4 o0, o1;
    o0.x = fmaf(acc[0], iv, r0.x);
    o0.y = fmaf(acc[1], iv, r0.y);
    o0.z = fmaf(acc[2], iv, r0.z);
    o0.w = fmaf(acc[3], iv, r0.w);
    o1.x = fmaf(acc[4], iv, r1.x);
    o1.y = fmaf(acc[5], iv, r1.y);
    o1.z = fmaf(acc[6], iv, r1.z);
    o1.w = fmaf(acc[7], iv, r1.w);
    if (RELU) {
      o0.x = fmaxf(o0.x, 0.f); o0.y = fmaxf(o0.y, 0.f);
      o0.z = fmaxf(o0.z, 0.f); o0.w = fmaxf(o0.w, 0.f);
      o1.x = fmaxf(o1.x, 0.f); o1.y = fmaxf(o1.y, 0.f);
      o1.z = fmaxf(o1.z, 0.f); o1.w = fmaxf(o1.w, 0.f);
    }
    float4* op = (float4*)(outp + (size_t)node * FOUT + c * 8);
    op[0] = o0;
    op[1] = o1;
  }
}

// ---------------- launch ----------------

extern "C" void kernel_launch(void* const* d_in, const int* in_sizes, int n_in,
                              void* d_out, int out_size, void* d_ws, size_t ws_size,
                              hipStream_t stream) {
  const float* x   = (const float*)d_in[0];
  const int*   ei  = (const int*)d_in[1];
  const float* Wl0 = (const float*)d_in[2];
  const float* bl0 = (const float*)d_in[3];
  const float* Wr0 = (const float*)d_in[4];
  const float* Wl1 = (const float*)d_in[5];
  const float* bl1 = (const float*)d_in[6];
  const float* Wr1 = (const float*)d_in[7];
  const float* Wl2 = (const float*)d_in[8];
  const float* bl2 = (const float*)d_in[9];
  const float* Wr2 = (const float*)d_in[10];
  float* out = (float*)d_out;

  const int N = in_sizes[0] / 128;
  const int E = in_sizes[1] / 2;
  const int* src = ei;
  const int* dst = ei + E;

  char* w = (char*)d_ws;
  auto alloc = [&](size_t bytes) {
    char* p = w;
    w += (bytes + 255) & ~(size_t)255;
    return p;
  };
  int*    cnt     = (int*)alloc((size_t)N * 4);
  int*    row_ptr = (int*)alloc((size_t)(N + 1) * 4);
  int*    rank    = (int*)alloc((size_t)E * 4);
  ushort* csr16   = (ushort*)alloc((size_t)E * 2 + 256);
  float*  inv     = (float*)alloc((size_t)N * 4);
  int*    partial = (int*)alloc((size_t)ceil_div(N, SCAN_CHUNK) * 4 + 256);
  ushort* Whi0    = (ushort*)alloc((size_t)4 * 256 * 4 * 16);
  ushort* Wlo0    = (ushort*)alloc((size_t)4 * 256 * 4 * 16);
  ushort* Whi1    = (ushort*)alloc((size_t)4 * 256 * 4 * 16);
  ushort* Wlo1    = (ushort*)alloc((size_t)4 * 256 * 4 * 16);
  ushort* Whi2    = (ushort*)alloc((size_t)4 * 128 * 4 * 16);
  ushort* Wlo2    = (ushort*)alloc((size_t)4 * 128 * 4 * 16);
  ushort* BZ      = (ushort*)alloc((size_t)N * 128 * 2);
  float*  BR      = (float*)alloc((size_t)N * 128 * 4);
  float*  B0      = (float*)alloc((size_t)N * 128 * 4);
  (void)ws_size; (void)n_in; (void)out_size;

  const int P = ceil_div(N, SCAN_CHUNK);

  // ---- weight packs ----
  k_pack<128><<<16, 256, 0, stream>>>(Wl0, Wr0, Whi0, Wlo0);
  k_pack<128><<<16, 256, 0, stream>>>(Wl1, Wr1, Whi1, Wlo1);
  k_pack<64><<<8, 256, 0, stream>>>(Wl2, Wr2, Whi2, Wlo2);

  // ---- CSR build (rank-based, single atomic pass) ----
  k_zero_int<<<ceil_div(N, 256), 256, 0, stream>>>(cnt, N);
  k_count_rank<<<ceil_div(E, 1024), 256, 0, stream>>>(dst, cnt, rank, E);
  k_blocksum<<<P, SCAN_BS, 0, stream>>>(cnt, partial, N);
  k_scan_partials<<<1, 256, 0, stream>>>(partial, P, row_ptr, N);
  k_scatter<<<P, SCAN_BS, 0, stream>>>(cnt, partial, row_ptr, inv, N);
  k_place<<<ceil_div(E, 1024), 256, 0, stream>>>(src, dst, rank, row_ptr, csr16, E);

  // ---- layer 0: x -> (Zb,R) -> H1 (B0) ----
  k_gemm2<128><<<ceil_div(N, 32), 256, 0, stream>>>(x, Whi0, Wlo0, bl0, BZ, BR, N);
  k_agg2<128, true><<<ceil_div(N, 4), 256, 0, stream>>>(BZ, BR, row_ptr, csr16, inv, B0, N);

  // ---- layer 1: B0 -> (Zb,R) -> H2 (B0) ----
  k_gemm2<128><<<ceil_div(N, 32), 256, 0, stream>>>(B0, Whi1, Wlo1, bl1, BZ, BR, N);
  k_agg2<128, true><<<ceil_div(N, 4), 256, 0, stream>>>(BZ, BR, row_ptr, csr16, inv, B0, N);

  // ---- layer 2: B0 -> (Zb,R) 64-wide -> out ----
  k_gemm2<64><<<ceil_div(N, 32), 256, 0, stream>>>(B0, Whi2, Wlo2, bl2, BZ, BR, N);
  k_agg2<64, false><<<ceil_div(N, 4), 256, 0, stream>>>(BZ, BR, row_ptr, csr16, inv, out, N);
}